// Round 7
// baseline (269.889 us; speedup 1.0000x reference)
//
#include <hip/hip_runtime.h>
#include <hip/hip_bf16.h>

#define B_ 2
#define C_ 512
#define HW_ 4096
#define K_ 512
#define EPS_ 1e-6f
#define SCALE_ 0.04419417382415922f   // 512^-0.5
#define NEG_INF_ (-1e30f)

typedef __attribute__((ext_vector_type(8))) __bf16 bf16x8;
typedef __attribute__((ext_vector_type(4))) float f32x4;
typedef __attribute__((ext_vector_type(16))) float f32x16;

__device__ __forceinline__ unsigned short f2bf(float f) {
  union { float f; unsigned u; } v; v.f = f;
  unsigned r = v.u + 0x7fffu + ((v.u >> 16) & 1u);
  return (unsigned short)(r >> 16);
}
__device__ __forceinline__ float bf2f(unsigned short h) {
  union { unsigned u; float f; } v; v.u = ((unsigned)h) << 16;
  return v.f;
}

// direct global->LDS DMA, 16B per lane. LDS dst = wave-uniform base + lane*16.
__device__ __forceinline__ void gld_lds16(const unsigned short* g, unsigned short* l) {
  __builtin_amdgcn_global_load_lds((const __attribute__((address_space(1))) void*)g,
                                   (__attribute__((address_space(3))) void*)l, 16, 0, 0);
}

// ------- fused: GroupNorm partial sums (blocks 0..1023, no atomics/memset)
//         + f32->bf16 weight cast (blocks 1024..2047) -------
// pstats[bid] = sum, pstats[1024+bid] = sumsq  (bid = bg*16 + rowblk)
__global__ void gn_cast(const float* __restrict__ x, float* __restrict__ pstats,
                        const float* __restrict__ s0, const float* __restrict__ s1,
                        const float* __restrict__ s2, const float* __restrict__ s3,
                        unsigned short* __restrict__ dst) {
  int bid = blockIdx.x;
  int t = threadIdx.x;
  if (bid < 1024) {
    int bg = bid >> 4, row = bid & 15;
    int b = bg >> 5, g = bg & 31;
    const float* base = x + ((size_t)(b * C_ + g * 16 + row)) * HW_;
    float s = 0.f, s2 = 0.f;
    #pragma unroll
    for (int i = 0; i < 4; ++i) {
      float4 v = *reinterpret_cast<const float4*>(base + (size_t)(t + i * 256) * 4);
      s  += v.x + v.y + v.z + v.w;
      s2 += v.x * v.x + v.y * v.y + v.z * v.z + v.w * v.w;
    }
    for (int off = 32; off; off >>= 1) { s += __shfl_down(s, off); s2 += __shfl_down(s2, off); }
    __shared__ float rs[4], rs2[4];
    int w = t >> 6;
    if ((t & 63) == 0) { rs[w] = s; rs2[w] = s2; }
    __syncthreads();
    if (t == 0) {
      pstats[bid] = rs[0] + rs[1] + rs[2] + rs[3];
      pstats[1024 + bid] = rs2[0] + rs2[1] + rs2[2] + rs2[3];
    }
  } else {
    int cid = bid - 1024;
    int which = cid >> 8, bx = cid & 255;
    const float* src = which == 0 ? s0 : which == 1 ? s1 : which == 2 ? s2 : s3;
    int i = (bx * 256 + t) * 4;
    float4 v = *reinterpret_cast<const float4*>(src + i);
    ushort4 o; o.x = f2bf(v.x); o.y = f2bf(v.y); o.z = f2bf(v.z); o.w = f2bf(v.w);
    *reinterpret_cast<ushort4*>(dst + (size_t)which * 262144 + i) = o;
  }
}

// ------------- normalize + transpose: x(b,c,n) f32 -> t(b,n,c) bf16 -------------
// reduces the 16 per-rowblock partials inline (L2-hot)
__global__ void build_t(const float* __restrict__ x, const float* __restrict__ pstats,
                        const float* __restrict__ gamma, const float* __restrict__ beta,
                        unsigned short* __restrict__ tb) {
  __shared__ float lds[64 * 69];
  int n0 = blockIdx.x * 64, c0 = blockIdx.y * 64, b = blockIdx.z;
  int t = threadIdx.x;
  {
    int cl = t >> 2, ch = t & 3;
    int c = c0 + cl;
    int bg = b * 32 + (c >> 4);
    float s = 0.f, s2v = 0.f;
    #pragma unroll
    for (int r = 0; r < 16; ++r) {
      s   += pstats[bg * 16 + r];
      s2v += pstats[1024 + bg * 16 + r];
    }
    float mean = s * (1.f / 65536.f);
    float var = s2v * (1.f / 65536.f) - mean * mean;
    float rstd = rsqrtf(var + EPS_);
    float ga = gamma[c] * rstd;
    float be = beta[c] - mean * ga;
    const float* xr = x + ((size_t)(b * C_ + c)) * HW_ + n0 + ch * 16;
    #pragma unroll
    for (int i = 0; i < 4; ++i) {
      float4 v = *reinterpret_cast<const float4*>(xr + i * 4);
      int nl = ch * 16 + i * 4;
      lds[cl * 69 + nl + 0] = v.x * ga + be;
      lds[cl * 69 + nl + 1] = v.y * ga + be;
      lds[cl * 69 + nl + 2] = v.z * ga + be;
      lds[cl * 69 + nl + 3] = v.w * ga + be;
    }
  }
  __syncthreads();
  {
    int nl = t >> 2, cw = t & 3;
    unsigned short* orow = tb + ((size_t)(b * HW_ + n0 + nl)) * C_ + c0 + cw * 16;
    #pragma unroll
    for (int i = 0; i < 4; ++i) {
      ushort4 o4;
      o4.x = f2bf(lds[(cw * 16 + i * 4 + 0) * 69 + nl]);
      o4.y = f2bf(lds[(cw * 16 + i * 4 + 1) * 69 + nl]);
      o4.z = f2bf(lds[(cw * 16 + i * 4 + 2) * 69 + nl]);
      o4.w = f2bf(lds[(cw * 16 + i * 4 + 3) * 69 + nl]);
      *reinterpret_cast<ushort4*>(orow + i * 4) = o4;
    }
  }
}

// ---------------- fused Q/K/V^T projections, one launch ----------------
// z = which*2 + b; which 0: q = t.wq^T (bias/col), 1: k (bias/col), 2: vT = wv.t^T (bias/row)
// XCD-aware remap: the 4 n-blocks sharing one t-tile land on the SAME XCD (T1),
// so the shared A/B t-operand is fetched into one L2, not four.
__global__ __launch_bounds__(256, 2) void gemm_qkv(
    const unsigned short* __restrict__ tb, const unsigned short* __restrict__ wqkv,
    const float* __restrict__ bq, const float* __restrict__ bk, const float* __restrict__ bv,
    unsigned short* __restrict__ qb, unsigned short* __restrict__ kb,
    unsigned short* __restrict__ vTb) {
  __shared__ unsigned short Al[2][128 * 64];
  __shared__ unsigned short Bl[2][128 * 64];
  // bijective remap of 768 blocks: xcd = f&7 fixed; i>>2 selects (y,z) combo, i&3 the x
  int f = blockIdx.x + 4 * (blockIdx.y + 32 * blockIdx.z);
  int xcd = f & 7, i = f >> 3;
  int bx = i & 3;
  int g = xcd * 24 + (i >> 2);     // 0..191
  int bz = g >> 5, by = g & 31;
  int which = bz >> 1, b = bz & 1;
  const unsigned short* Ab = (which < 2) ? (tb + (size_t)b * HW_ * K_) : (wqkv + 2 * 262144);
  const unsigned short* Bb = (which < 2) ? (wqkv + which * 262144) : (tb + (size_t)b * HW_ * K_);
  int m0 = (which < 2) ? by * 128 : bx * 128;
  int n0 = (which < 2) ? bx * 128 : by * 128;
  int N = (which < 2) ? 512 : HW_;
  unsigned short* Cb = (which == 0) ? (qb + (size_t)b * HW_ * K_)
                     : (which == 1) ? (kb + (size_t)b * HW_ * K_)
                                    : (vTb + (size_t)b * C_ * HW_);
  const float* bias = (which == 0) ? bq : (which == 1) ? bk : bv;
  int t = threadIdx.x, lane = t & 63, w = t >> 6;
  int l15 = lane & 15, quad = lane >> 4;
  int mw = (w & 1) * 64, nw = (w >> 1) * 64;
  int sr8 = lane >> 3, sb = lane & 7;
  f32x4 acc[4][4] = {};

  #define G_STAGE(KC) do {                                                          \
    int pb = (KC) & 1;                                                              \
    _Pragma("unroll")                                                               \
    for (int q = 0; q < 4; ++q) {                                                   \
      int row = w * 32 + q * 8 + sr8;                                               \
      int gb = sb ^ (row & 7);                                                      \
      gld_lds16(Ab + (size_t)(m0 + row) * K_ + (KC) * 64 + gb * 8, &Al[pb][(w * 32 + q * 8) * 64]); \
      gld_lds16(Bb + (size_t)(n0 + row) * K_ + (KC) * 64 + gb * 8, &Bl[pb][(w * 32 + q * 8) * 64]); \
    }                                                                               \
  } while (0)

  G_STAGE(0);
  __syncthreads();
  for (int kc = 0; kc < 8; ++kc) {
    if (kc < 7) G_STAGE(kc + 1);
    const unsigned short* Ac = Al[kc & 1];
    const unsigned short* Bc = Bl[kc & 1];
    #pragma unroll
    for (int kk = 0; kk < 2; ++kk) {
      bf16x8 af[4];
      #pragma unroll
      for (int mt = 0; mt < 4; ++mt)
        af[mt] = *reinterpret_cast<const bf16x8*>(
            &Ac[(mw + mt * 16 + l15) * 64 + (((kk * 4 + quad) ^ (l15 & 7)) << 3)]);
      #pragma unroll
      for (int nt = 0; nt < 4; ++nt) {
        bf16x8 bfr = *reinterpret_cast<const bf16x8*>(
            &Bc[(nw + nt * 16 + l15) * 64 + (((kk * 4 + quad) ^ (l15 & 7)) << 3)]);
        #pragma unroll
        for (int mt = 0; mt < 4; ++mt)
          acc[mt][nt] = __builtin_amdgcn_mfma_f32_16x16x32_bf16(af[mt], bfr, acc[mt][nt], 0, 0, 0);
      }
    }
    __syncthreads();
  }
  #undef G_STAGE
  #pragma unroll
  for (int mt = 0; mt < 4; ++mt)
    #pragma unroll
    for (int nt = 0; nt < 4; ++nt)
      #pragma unroll
      for (int rr = 0; rr < 4; ++rr) {
        int row = m0 + mw + mt * 16 + quad * 4 + rr;
        int col = n0 + nw + nt * 16 + l15;
        float v = acc[mt][nt][rr] + ((which < 2) ? bias[col] : bias[row]);
        Cb[(size_t)row * N + col] = f2bf(v);
      }
}

// ---------------- final projection + residual, with fused opart merge ----------------
// out[z][m][n] = x[z][m][n] + bp[m] + wp[m] . merged_o[z][n]
// B-tile reg-staged: merge two opart halves with per-row softmax weights; stride-68 pad.
// (B-sharing blocks already co-XCD under default mapping: ids differ by 32 == 0 mod 8.)
__global__ __launch_bounds__(256, 2) void gemm_fin(
    const unsigned short* __restrict__ A,            // wpb 512x512 bf16
    const unsigned short* __restrict__ opart,        // 4 parts (jh*2+z)
    const float* __restrict__ mpart, const float* __restrict__ lpart,
    const float* __restrict__ bias, const float* __restrict__ resid,
    float* __restrict__ out) {
  __shared__ unsigned short Al[2][128 * 64];
  __shared__ unsigned short Bl[2][128 * 68];   // padded: row stride 68 shorts (no XOR needed)
  int z = blockIdx.z;
  int n0 = blockIdx.x * 128, m0 = blockIdx.y * 128;
  int t = threadIdx.x, lane = t & 63, w = t >> 6;
  int l15 = lane & 15, quad = lane >> 4;
  int mw = (w & 1) * 64, nw = (w >> 1) * 64;
  int sr8 = lane >> 3, sb = lane & 7;
  f32x4 acc[4][4] = {};

  // per-thread merge weights for the 4 B-rows it stages
  float w0[4], w1[4];
  int nrow[4];
  #pragma unroll
  for (int q = 0; q < 4; ++q) {
    int n = n0 + w * 32 + q * 8 + sr8;
    nrow[q] = n;
    float ma = mpart[(size_t)z * HW_ + n], mb = mpart[(size_t)(2 + z) * HW_ + n];
    float la = lpart[(size_t)z * HW_ + n], lb = lpart[(size_t)(2 + z) * HW_ + n];
    float M = fmaxf(ma, mb);
    float ea = __expf(ma - M), eb = __expf(mb - M);
    float iv = 1.f / (la * ea + lb * eb);
    w0[q] = ea * iv; w1[q] = eb * iv;
  }
  const unsigned short* p0 = opart + (size_t)z * HW_ * 512;
  const unsigned short* p1 = opart + (size_t)(2 + z) * HW_ * 512;

  #define STAGE_A(KC) do {                                                          \
    int pb = (KC) & 1;                                                              \
    _Pragma("unroll")                                                               \
    for (int q = 0; q < 4; ++q) {                                                   \
      int row = w * 32 + q * 8 + sr8;                                               \
      int gb = sb ^ (row & 7);                                                      \
      gld_lds16(A + (size_t)(m0 + row) * K_ + (KC) * 64 + gb * 8, &Al[pb][(w * 32 + q * 8) * 64]); \
    }                                                                               \
  } while (0)

  #define STAGE_B(KC) do {                                                          \
    int pb = (KC) & 1;                                                              \
    _Pragma("unroll")                                                               \
    for (int q = 0; q < 4; ++q) {                                                   \
      int row = w * 32 + q * 8 + sr8;                                               \
      size_t goff = (size_t)nrow[q] * 512 + (KC) * 64 + sb * 8;                     \
      uint4 u0 = *reinterpret_cast<const uint4*>(p0 + goff);                        \
      uint4 u1 = *reinterpret_cast<const uint4*>(p1 + goff);                        \
      uint4 o4;                                                                     \
      unsigned* a0 = reinterpret_cast<unsigned*>(&u0);                              \
      unsigned* a1 = reinterpret_cast<unsigned*>(&u1);                              \
      unsigned* od = reinterpret_cast<unsigned*>(&o4);                              \
      _Pragma("unroll")                                                             \
      for (int j = 0; j < 4; ++j) {                                                 \
        float lo = bf2f((unsigned short)(a0[j] & 0xffffu)) * w0[q]                  \
                 + bf2f((unsigned short)(a1[j] & 0xffffu)) * w1[q];                 \
        float hi = bf2f((unsigned short)(a0[j] >> 16)) * w0[q]                      \
                 + bf2f((unsigned short)(a1[j] >> 16)) * w1[q];                     \
        od[j] = (unsigned)f2bf(lo) | ((unsigned)f2bf(hi) << 16);                    \
      }                                                                             \
      *reinterpret_cast<uint4*>(&Bl[pb][row * 68 + sb * 8]) = o4;                   \
    }                                                                               \
  } while (0)

  STAGE_A(0);
  STAGE_B(0);
  __syncthreads();
  for (int kc = 0; kc < 8; ++kc) {
    if (kc < 7) { STAGE_A(kc + 1); STAGE_B(kc + 1); }
    const unsigned short* Ac = Al[kc & 1];
    const unsigned short* Bc = Bl[kc & 1];
    #pragma unroll
    for (int kk = 0; kk < 2; ++kk) {
      bf16x8 af[4];
      #pragma unroll
      for (int mt = 0; mt < 4; ++mt)
        af[mt] = *reinterpret_cast<const bf16x8*>(
            &Ac[(mw + mt * 16 + l15) * 64 + (((kk * 4 + quad) ^ (l15 & 7)) << 3)]);
      #pragma unroll
      for (int nt = 0; nt < 4; ++nt) {
        bf16x8 bfr = *reinterpret_cast<const bf16x8*>(
            &Bc[(nw + nt * 16 + l15) * 68 + ((kk * 4 + quad) << 3)]);
        #pragma unroll
        for (int mt = 0; mt < 4; ++mt)
          acc[mt][nt] = __builtin_amdgcn_mfma_f32_16x16x32_bf16(af[mt], bfr, acc[mt][nt], 0, 0, 0);
      }
    }
    __syncthreads();
  }
  #undef STAGE_A
  #undef STAGE_B
  #pragma unroll
  for (int mt = 0; mt < 4; ++mt)
    #pragma unroll
    for (int nt = 0; nt < 4; ++nt)
      #pragma unroll
      for (int rr = 0; rr < 4; ++rr) {
        int row = m0 + mw + mt * 16 + quad * 4 + rr;
        int col = n0 + nw + nt * 16 + l15;
        size_t idx = (size_t)z * (C_ * HW_) + (size_t)row * HW_ + col;
        out[idx] = acc[mt][nt][rr] + bias[row] + resid[idx];
      }
}

// ------- flash attention (r10-verified form + XCD grouping): Br=64, Bc=256; async DMA +
// XOR swizzle, 2 rotating buffers, depth-1 prefetch, __syncthreads barriers, setprio.
// T1 remap: each (jh,b) group's 64 qt-blocks land on a dedicated XCD PAIR, so the
// shared 4MB K/V half is fetched into 2 L2s instead of 8 -> staging becomes L2-hit.
__global__ __launch_bounds__(512, 2) void attn(
    const unsigned short* __restrict__ qg, const unsigned short* __restrict__ kg,
    const unsigned short* __restrict__ vg,  // vT: (b, c, n)
    unsigned short* __restrict__ opart, float* __restrict__ mpart, float* __restrict__ lpart) {
  __shared__ unsigned short KVb[2 * 16384];   // 2 x 32KB chunk buffers (128 rows x 128 cols)
  __shared__ unsigned short Pl[64 * 264];     // 33792 B
  __shared__ float sm_m[64], sm_l[64], sm_alpha[64], sm_red[128];
  // bijective remap of 256 blocks: xcd = f&7; pair p = xcd>>1 -> (jh,b); qt = slot*2 + (xcd&1)
  int f = blockIdx.x + 64 * (blockIdx.y + 2 * blockIdx.z);
  int xcd0 = f & 7, s0 = f >> 3;
  int p = xcd0 >> 1;
  int qt = s0 * 2 + (xcd0 & 1);
  int jh = p & 1, b = p >> 1;
  int t = threadIdx.x, lane = t & 63, w = t >> 6;
  int l15 = lane & 15, quad = lane >> 4;
  int l31 = lane & 31, hl = lane >> 5;
  int rw = w & 3, cw = w >> 2;      // S phase: 4 row-groups(16) x 2 col-halves
  int rw2 = w & 1, dg = w >> 1;     // PV phase: 2 row-groups(32) x 4 d-slots
  int m0 = qt * 64;
  if (t < 64) { sm_m[t] = NEG_INF_; sm_l[t] = 0.f; }

  // staging geometry: thread stages 4 x 16B; wave w covers 1KB blocks w*4+q (4 rows each)
  int st_r[4], st_kb[4];
  #pragma unroll
  for (int q = 0; q < 4; ++q) {
    int blk = w * 4 + q;
    st_r[q] = blk * 4 + (lane >> 4);          // row 0..127 within chunk
    st_kb[q] = (lane & 15) ^ (st_r[q] & 7);   // logical 16B block (col/8)
  }

  #define STAGE_K(JC, KC, J0) do {                                                  \
    const unsigned short* gb = kg + ((size_t)(b * HW_ + (J0) + (JC) * 128)) * K_ + (KC) * 128; \
    unsigned short* lb = KVb + ((((JC) * 4 + (KC)) & 1) << 14);                     \
    _Pragma("unroll")                                                               \
    for (int q = 0; q < 4; ++q)                                                     \
      gld_lds16(gb + (size_t)st_r[q] * K_ + st_kb[q] * 8, lb + (w * 4 + q) * 512);  \
  } while (0)

  // chunk index in PV = jc*4 + dc -> buffer parity = dc&1
  #define STAGE_V(DC, JC, J0) do {                                                 \
    const unsigned short* gb = vg + ((size_t)(b * K_ + (DC) * 128)) * HW_ + (J0) + (JC) * 128; \
    unsigned short* lb = KVb + (((DC) & 1) << 14);                                  \
    _Pragma("unroll")                                                               \
    for (int q = 0; q < 4; ++q)                                                     \
      gld_lds16(gb + (size_t)st_r[q] * HW_ + st_kb[q] * 8, lb + (w * 4 + q) * 512); \
  } while (0)

  bf16x8 qa[16];
  {
    const unsigned short* qrow = qg + ((size_t)(b * HW_ + m0 + rw * 16 + l15)) * K_ + quad * 8;
    #pragma unroll
    for (int kk = 0; kk < 16; ++kk)
      qa[kk] = *reinterpret_cast<const bf16x8*>(qrow + kk * 32);
  }
  f32x16 acc_o[4] = {};    // [dc]: d = dc*128 + dg*32 + l31

  int j0 = jh * 2048;
  STAGE_K(0, 0, j0);       // chunk 0 in flight
  __syncthreads();         // drains chunk 0; publishes sm init

  for (int it = 0; it < 8; ++it, j0 += 256) {
    f32x4 acc_s[8] = {};
    // ===== S phases: 8 chunks (jc 0..1) x (kc 0..3) =====
    #pragma unroll
    for (int c = 0; c < 8; ++c) {
      int jc = c >> 2, kc = c & 3;
      if (c < 7) { STAGE_K((c + 1) >> 2, (c + 1) & 3, j0); }
      else       { STAGE_V(0, 0, j0); }   // PV chunk 0 (parity 0)
      const unsigned short* bufc = KVb + ((c & 1) << 14);
      __builtin_amdgcn_s_setprio(1);
      #pragma unroll
      for (int kk = 0; kk < 4; ++kk)
        #pragma unroll
        for (int ct = 0; ct < 4; ++ct) {
          int jr = cw * 64 + ct * 16 + l15;
          bf16x8 bfr = *reinterpret_cast<const bf16x8*>(
              &bufc[jr * 128 + (((kk * 4 + quad) ^ (l15 & 7)) << 3)]);
          acc_s[jc * 4 + ct] = __builtin_amdgcn_mfma_f32_16x16x32_bf16(qa[kc * 4 + kk], bfr, acc_s[jc * 4 + ct], 0, 0, 0);
        }
      __builtin_amdgcn_s_setprio(0);
      __syncthreads();
    }
    // ===== softmax =====
    float mx[4];
    #pragma unroll
    for (int rr = 0; rr < 4; ++rr) {
      float m = NEG_INF_;
      #pragma unroll
      for (int s = 0; s < 8; ++s) {
        acc_s[s][rr] *= SCALE_;
        m = fmaxf(m, acc_s[s][rr]);
      }
      mx[rr] = m;
    }
    #pragma unroll
    for (int off = 1; off < 16; off <<= 1)
      #pragma unroll
      for (int rr = 0; rr < 4; ++rr)
        mx[rr] = fmaxf(mx[rr], __shfl_xor(mx[rr], off));
    if (l15 == 0)
      #pragma unroll
      for (int rr = 0; rr < 4; ++rr)
        sm_red[cw * 64 + rw * 16 + quad * 4 + rr] = mx[rr];
    __syncthreads();
    if (t < 64) {
      float mnew = fmaxf(sm_m[t], fmaxf(sm_red[t], sm_red[64 + t]));
      sm_alpha[t] = __expf(sm_m[t] - mnew);
      sm_m[t] = mnew;
    }
    __syncthreads();
    float sum[4] = {0.f, 0.f, 0.f, 0.f};
    #pragma unroll
    for (int s = 0; s < 8; ++s)
      #pragma unroll
      for (int rr = 0; rr < 4; ++rr) {
        int rowl = rw * 16 + quad * 4 + rr;
        float p = __expf(acc_s[s][rr] - sm_m[rowl]);
        sum[rr] += p;
        Pl[rowl * 264 + (s >> 2) * 128 + cw * 64 + (s & 3) * 16 + l15] = f2bf(p);
      }
    #pragma unroll
    for (int off = 1; off < 16; off <<= 1)
      #pragma unroll
      for (int rr = 0; rr < 4; ++rr)
        sum[rr] += __shfl_xor(sum[rr], off);
    if (l15 == 0)
      #pragma unroll
      for (int rr = 0; rr < 4; ++rr)
        sm_red[cw * 64 + rw * 16 + quad * 4 + rr] = sum[rr];
    __syncthreads();
    if (t < 64)
      sm_l[t] = sm_l[t] * sm_alpha[t] + sm_red[t] + sm_red[64 + t];
    // rescale O by alpha (32x32 C/D row mapping)
    #pragma unroll
    for (int r16 = 0; r16 < 16; ++r16) {
      int row = rw2 * 32 + (r16 & 3) + 8 * (r16 >> 2) + 4 * hl;
      float a = sm_alpha[row];
      #pragma unroll
      for (int dc = 0; dc < 4; ++dc)
        acc_o[dc][r16] *= a;
    }
    // ===== PV phases: 8 chunks, dc-inner (c: jc=c>>2, dc=c&3); pa_r reused across dc =====
    bf16x8 pa_r[8];
    #pragma unroll
    for (int c = 0; c < 8; ++c) {
      int jc = c >> 2, dc = c & 3;
      if ((c & 3) == 0) {
        #pragma unroll
        for (int ksx = 0; ksx < 8; ++ksx)
          pa_r[ksx] = *reinterpret_cast<const bf16x8*>(
              &Pl[(rw2 * 32 + l31) * 264 + jc * 128 + ksx * 16 + hl * 8]);
      }
      if (c < 7)          { STAGE_V((c + 1) & 3, (c + 1) >> 2, j0); }
      else if (it < 7)    { STAGE_K(0, 0, j0 + 256); }
      const unsigned short* bufc = KVb + ((c & 1) << 14);
      __builtin_amdgcn_s_setprio(1);
      #pragma unroll
      for (int ksx = 0; ksx < 8; ++ksx) {
        bf16x8 vb = *reinterpret_cast<const bf16x8*>(
            &bufc[(dg * 32 + l31) * 128 + (((ksx * 2 + hl) ^ (l31 & 7)) << 3)]);
        acc_o[dc] = __builtin_amdgcn_mfma_f32_32x32x16_bf16(pa_r[ksx], vb, acc_o[dc], 0, 0, 0);
      }
      __builtin_amdgcn_s_setprio(0);
      __syncthreads();
    }
  }
  #undef STAGE_K
  #undef STAGE_V
  // write partials (unnormalized O in bf16, running m and l)
  int part = jh * 2 + b;
  unsigned short* ob = opart + ((size_t)part * HW_ + m0) * 512;
  #pragma unroll
  for (int dc = 0; dc < 4; ++dc) {
    int d = dc * 128 + dg * 32 + l31;
    #pragma unroll
    for (int r16 = 0; r16 < 16; ++r16) {
      int row = rw2 * 32 + (r16 & 3) + 8 * (r16 >> 2) + 4 * hl;
      ob[(size_t)row * 512 + d] = f2bf(acc_o[dc][r16]);
    }
  }
  if (t < 64) {
    mpart[(size_t)part * HW_ + m0 + t] = sm_m[t];
    lpart[(size_t)part * HW_ + m0 + t] = sm_l[t];
  }
}

extern "C" void kernel_launch(void* const* d_in, const int* in_sizes, int n_in,
                              void* d_out, int out_size, void* d_ws, size_t ws_size,
                              hipStream_t stream) {
  const float* x     = (const float*)d_in[0];
  const float* gamma = (const float*)d_in[1];
  const float* beta  = (const float*)d_in[2];
  const float* wq    = (const float*)d_in[3];
  const float* bq    = (const float*)d_in[4];
  const float* wk    = (const float*)d_in[5];
  const float* bk    = (const float*)d_in[6];
  const float* wv    = (const float*)d_in[7];
  const float* bv    = (const float*)d_in[8];
  const float* wp    = (const float*)d_in[9];
  const float* bp    = (const float*)d_in[10];
  float* out = (float*)d_out;

  char* ws = (char*)d_ws;
  size_t o = 0;
  float* pstats         = (float*)(ws + o);          o += 8192;      // 2048 f32 partials
  unsigned short* tb    = (unsigned short*)(ws + o); o += 8388608;
  unsigned short* qb    = (unsigned short*)(ws + o); o += 8388608;
  unsigned short* kb    = (unsigned short*)(ws + o); o += 8388608;
  unsigned short* vTb   = (unsigned short*)(ws + o); o += 8388608;
  unsigned short* wqb   = (unsigned short*)(ws + o); o += 524288;
  unsigned short* wkb   = (unsigned short*)(ws + o); o += 524288;
  unsigned short* wvb   = (unsigned short*)(ws + o); o += 524288;
  unsigned short* wpb   = (unsigned short*)(ws + o); o += 524288;
  unsigned short* opart = (unsigned short*)(ws + o); o += 16777216;  // 4 parts bf16
  float* mpart          = (float*)(ws + o);          o += 65536;
  float* lpart          = (float*)(ws + o);          o += 65536;

  // fused groupnorm partial sums + weight cast (no memset, no atomics)
  gn_cast<<<2048, 256, 0, stream>>>(x, pstats, wq, wk, wv, wp, wqb);
  build_t<<<dim3(64, 8, 2), 256, 0, stream>>>(x, pstats, gamma, beta, tb);
  // fused q,k,vT projections (XCD-grouped)
  gemm_qkv<<<dim3(4, 32, 6), 256, 0, stream>>>(tb, wqb, bq, bk, bv, qb, kb, vTb);
  attn<<<dim3(64, 2, 2), 512, 0, stream>>>(qb, kb, vTb, opart, mpart, lpart);
  // final projection with fused partial-merge + residual
  gemm_fin<<<dim3(32, 4, 2), 256, 0, stream>>>(wpb, opart, mpart, lpart, bp, x, out);
}

// Round 8
// 264.978 us; speedup vs baseline: 1.0185x; 1.0185x over previous
//
#include <hip/hip_runtime.h>
#include <hip/hip_bf16.h>

#define B_ 2
#define C_ 512
#define HW_ 4096
#define K_ 512
#define EPS_ 1e-6f
#define SCALE_ 0.04419417382415922f   // 512^-0.5
#define NEG_INF_ (-1e30f)

typedef __attribute__((ext_vector_type(8))) __bf16 bf16x8;
typedef __attribute__((ext_vector_type(4))) float f32x4;
typedef __attribute__((ext_vector_type(16))) float f32x16;

__device__ __forceinline__ unsigned short f2bf(float f) {
  union { float f; unsigned u; } v; v.f = f;
  unsigned r = v.u + 0x7fffu + ((v.u >> 16) & 1u);
  return (unsigned short)(r >> 16);
}
__device__ __forceinline__ float bf2f(unsigned short h) {
  union { unsigned u; float f; } v; v.u = ((unsigned)h) << 16;
  return v.f;
}

// direct global->LDS DMA, 16B per lane. LDS dst = wave-uniform base + lane*16.
__device__ __forceinline__ void gld_lds16(const unsigned short* g, unsigned short* l) {
  __builtin_amdgcn_global_load_lds((const __attribute__((address_space(1))) void*)g,
                                   (__attribute__((address_space(3))) void*)l, 16, 0, 0);
}

// ------- fused: GroupNorm partial sums (blocks 0..1023, no atomics/memset)
//         + f32->bf16 weight cast (blocks 1024..2047) -------
// pstats[bid] = sum, pstats[1024+bid] = sumsq  (bid = bg*16 + rowblk)
__global__ void gn_cast(const float* __restrict__ x, float* __restrict__ pstats,
                        const float* __restrict__ s0, const float* __restrict__ s1,
                        const float* __restrict__ s2, const float* __restrict__ s3,
                        unsigned short* __restrict__ dst) {
  int bid = blockIdx.x;
  int t = threadIdx.x;
  if (bid < 1024) {
    int bg = bid >> 4, row = bid & 15;
    int b = bg >> 5, g = bg & 31;
    const float* base = x + ((size_t)(b * C_ + g * 16 + row)) * HW_;
    float s = 0.f, s2 = 0.f;
    #pragma unroll
    for (int i = 0; i < 4; ++i) {
      float4 v = *reinterpret_cast<const float4*>(base + (size_t)(t + i * 256) * 4);
      s  += v.x + v.y + v.z + v.w;
      s2 += v.x * v.x + v.y * v.y + v.z * v.z + v.w * v.w;
    }
    for (int off = 32; off; off >>= 1) { s += __shfl_down(s, off); s2 += __shfl_down(s2, off); }
    __shared__ float rs[4], rs2[4];
    int w = t >> 6;
    if ((t & 63) == 0) { rs[w] = s; rs2[w] = s2; }
    __syncthreads();
    if (t == 0) {
      pstats[bid] = rs[0] + rs[1] + rs[2] + rs[3];
      pstats[1024 + bid] = rs2[0] + rs2[1] + rs2[2] + rs2[3];
    }
  } else {
    int cid = bid - 1024;
    int which = cid >> 8, bx = cid & 255;
    const float* src = which == 0 ? s0 : which == 1 ? s1 : which == 2 ? s2 : s3;
    int i = (bx * 256 + t) * 4;
    float4 v = *reinterpret_cast<const float4*>(src + i);
    ushort4 o; o.x = f2bf(v.x); o.y = f2bf(v.y); o.z = f2bf(v.z); o.w = f2bf(v.w);
    *reinterpret_cast<ushort4*>(dst + (size_t)which * 262144 + i) = o;
  }
}

// ------------- normalize + transpose: x(b,c,n) f32 -> t(b,n,c) bf16 -------------
// reduces the 16 per-rowblock partials inline (L2-hot)
__global__ void build_t(const float* __restrict__ x, const float* __restrict__ pstats,
                        const float* __restrict__ gamma, const float* __restrict__ beta,
                        unsigned short* __restrict__ tb) {
  __shared__ float lds[64 * 69];
  int n0 = blockIdx.x * 64, c0 = blockIdx.y * 64, b = blockIdx.z;
  int t = threadIdx.x;
  {
    int cl = t >> 2, ch = t & 3;
    int c = c0 + cl;
    int bg = b * 32 + (c >> 4);
    float s = 0.f, s2v = 0.f;
    #pragma unroll
    for (int r = 0; r < 16; ++r) {
      s   += pstats[bg * 16 + r];
      s2v += pstats[1024 + bg * 16 + r];
    }
    float mean = s * (1.f / 65536.f);
    float var = s2v * (1.f / 65536.f) - mean * mean;
    float rstd = rsqrtf(var + EPS_);
    float ga = gamma[c] * rstd;
    float be = beta[c] - mean * ga;
    const float* xr = x + ((size_t)(b * C_ + c)) * HW_ + n0 + ch * 16;
    #pragma unroll
    for (int i = 0; i < 4; ++i) {
      float4 v = *reinterpret_cast<const float4*>(xr + i * 4);
      int nl = ch * 16 + i * 4;
      lds[cl * 69 + nl + 0] = v.x * ga + be;
      lds[cl * 69 + nl + 1] = v.y * ga + be;
      lds[cl * 69 + nl + 2] = v.z * ga + be;
      lds[cl * 69 + nl + 3] = v.w * ga + be;
    }
  }
  __syncthreads();
  {
    int nl = t >> 2, cw = t & 3;
    unsigned short* orow = tb + ((size_t)(b * HW_ + n0 + nl)) * C_ + c0 + cw * 16;
    #pragma unroll
    for (int i = 0; i < 4; ++i) {
      ushort4 o4;
      o4.x = f2bf(lds[(cw * 16 + i * 4 + 0) * 69 + nl]);
      o4.y = f2bf(lds[(cw * 16 + i * 4 + 1) * 69 + nl]);
      o4.z = f2bf(lds[(cw * 16 + i * 4 + 2) * 69 + nl]);
      o4.w = f2bf(lds[(cw * 16 + i * 4 + 3) * 69 + nl]);
      *reinterpret_cast<ushort4*>(orow + i * 4) = o4;
    }
  }
}

// ---------------- fused Q/K/V^T projections, one launch ----------------
// z = which*2 + b; which 0: q = t.wq^T (bias/col), 1: k (bias/col), 2: vT = wv.t^T (bias/row)
// XCD-aware remap: the 4 n-blocks sharing one t-tile land on the SAME XCD (T1),
// so the shared A/B t-operand is fetched into one L2, not four. (r14: ~5 us win)
__global__ __launch_bounds__(256, 2) void gemm_qkv(
    const unsigned short* __restrict__ tb, const unsigned short* __restrict__ wqkv,
    const float* __restrict__ bq, const float* __restrict__ bk, const float* __restrict__ bv,
    unsigned short* __restrict__ qb, unsigned short* __restrict__ kb,
    unsigned short* __restrict__ vTb) {
  __shared__ unsigned short Al[2][128 * 64];
  __shared__ unsigned short Bl[2][128 * 64];
  // bijective remap of 768 blocks: xcd = f&7 fixed; i>>2 selects (y,z) combo, i&3 the x
  int f = blockIdx.x + 4 * (blockIdx.y + 32 * blockIdx.z);
  int xcd = f & 7, i = f >> 3;
  int bx = i & 3;
  int g = xcd * 24 + (i >> 2);     // 0..191
  int bz = g >> 5, by = g & 31;
  int which = bz >> 1, b = bz & 1;
  const unsigned short* Ab = (which < 2) ? (tb + (size_t)b * HW_ * K_) : (wqkv + 2 * 262144);
  const unsigned short* Bb = (which < 2) ? (wqkv + which * 262144) : (tb + (size_t)b * HW_ * K_);
  int m0 = (which < 2) ? by * 128 : bx * 128;
  int n0 = (which < 2) ? bx * 128 : by * 128;
  int N = (which < 2) ? 512 : HW_;
  unsigned short* Cb = (which == 0) ? (qb + (size_t)b * HW_ * K_)
                     : (which == 1) ? (kb + (size_t)b * HW_ * K_)
                                    : (vTb + (size_t)b * C_ * HW_);
  const float* bias = (which == 0) ? bq : (which == 1) ? bk : bv;
  int t = threadIdx.x, lane = t & 63, w = t >> 6;
  int l15 = lane & 15, quad = lane >> 4;
  int mw = (w & 1) * 64, nw = (w >> 1) * 64;
  int sr8 = lane >> 3, sb = lane & 7;
  f32x4 acc[4][4] = {};

  #define G_STAGE(KC) do {                                                          \
    int pb = (KC) & 1;                                                              \
    _Pragma("unroll")                                                               \
    for (int q = 0; q < 4; ++q) {                                                   \
      int row = w * 32 + q * 8 + sr8;                                               \
      int gb = sb ^ (row & 7);                                                      \
      gld_lds16(Ab + (size_t)(m0 + row) * K_ + (KC) * 64 + gb * 8, &Al[pb][(w * 32 + q * 8) * 64]); \
      gld_lds16(Bb + (size_t)(n0 + row) * K_ + (KC) * 64 + gb * 8, &Bl[pb][(w * 32 + q * 8) * 64]); \
    }                                                                               \
  } while (0)

  G_STAGE(0);
  __syncthreads();
  for (int kc = 0; kc < 8; ++kc) {
    if (kc < 7) G_STAGE(kc + 1);
    const unsigned short* Ac = Al[kc & 1];
    const unsigned short* Bc = Bl[kc & 1];
    #pragma unroll
    for (int kk = 0; kk < 2; ++kk) {
      bf16x8 af[4];
      #pragma unroll
      for (int mt = 0; mt < 4; ++mt)
        af[mt] = *reinterpret_cast<const bf16x8*>(
            &Ac[(mw + mt * 16 + l15) * 64 + (((kk * 4 + quad) ^ (l15 & 7)) << 3)]);
      #pragma unroll
      for (int nt = 0; nt < 4; ++nt) {
        bf16x8 bfr = *reinterpret_cast<const bf16x8*>(
            &Bc[(nw + nt * 16 + l15) * 64 + (((kk * 4 + quad) ^ (l15 & 7)) << 3)]);
        #pragma unroll
        for (int mt = 0; mt < 4; ++mt)
          acc[mt][nt] = __builtin_amdgcn_mfma_f32_16x16x32_bf16(af[mt], bfr, acc[mt][nt], 0, 0, 0);
      }
    }
    __syncthreads();
  }
  #undef G_STAGE
  #pragma unroll
  for (int mt = 0; mt < 4; ++mt)
    #pragma unroll
    for (int nt = 0; nt < 4; ++nt)
      #pragma unroll
      for (int rr = 0; rr < 4; ++rr) {
        int row = m0 + mw + mt * 16 + quad * 4 + rr;
        int col = n0 + nw + nt * 16 + l15;
        float v = acc[mt][nt][rr] + ((which < 2) ? bias[col] : bias[row]);
        Cb[(size_t)row * N + col] = f2bf(v);
      }
}

// ---------------- final projection + residual, with fused opart merge ----------------
// out[z][m][n] = x[z][m][n] + bp[m] + wp[m] . merged_o[z][n]
// B-tile reg-staged: merge two opart halves with per-row softmax weights; stride-68 pad.
__global__ __launch_bounds__(256, 2) void gemm_fin(
    const unsigned short* __restrict__ A,            // wpb 512x512 bf16
    const unsigned short* __restrict__ opart,        // 4 parts (jh*2+z)
    const float* __restrict__ mpart, const float* __restrict__ lpart,
    const float* __restrict__ bias, const float* __restrict__ resid,
    float* __restrict__ out) {
  __shared__ unsigned short Al[2][128 * 64];
  __shared__ unsigned short Bl[2][128 * 68];   // padded: row stride 68 shorts (no XOR needed)
  int z = blockIdx.z;
  int n0 = blockIdx.x * 128, m0 = blockIdx.y * 128;
  int t = threadIdx.x, lane = t & 63, w = t >> 6;
  int l15 = lane & 15, quad = lane >> 4;
  int mw = (w & 1) * 64, nw = (w >> 1) * 64;
  int sr8 = lane >> 3, sb = lane & 7;
  f32x4 acc[4][4] = {};

  // per-thread merge weights for the 4 B-rows it stages
  float w0[4], w1[4];
  int nrow[4];
  #pragma unroll
  for (int q = 0; q < 4; ++q) {
    int n = n0 + w * 32 + q * 8 + sr8;
    nrow[q] = n;
    float ma = mpart[(size_t)z * HW_ + n], mb = mpart[(size_t)(2 + z) * HW_ + n];
    float la = lpart[(size_t)z * HW_ + n], lb = lpart[(size_t)(2 + z) * HW_ + n];
    float M = fmaxf(ma, mb);
    float ea = __expf(ma - M), eb = __expf(mb - M);
    float iv = 1.f / (la * ea + lb * eb);
    w0[q] = ea * iv; w1[q] = eb * iv;
  }
  const unsigned short* p0 = opart + (size_t)z * HW_ * 512;
  const unsigned short* p1 = opart + (size_t)(2 + z) * HW_ * 512;

  #define STAGE_A(KC) do {                                                          \
    int pb = (KC) & 1;                                                              \
    _Pragma("unroll")                                                               \
    for (int q = 0; q < 4; ++q) {                                                   \
      int row = w * 32 + q * 8 + sr8;                                               \
      int gb = sb ^ (row & 7);                                                      \
      gld_lds16(A + (size_t)(m0 + row) * K_ + (KC) * 64 + gb * 8, &Al[pb][(w * 32 + q * 8) * 64]); \
    }                                                                               \
  } while (0)

  #define STAGE_B(KC) do {                                                          \
    int pb = (KC) & 1;                                                              \
    _Pragma("unroll")                                                               \
    for (int q = 0; q < 4; ++q) {                                                   \
      int row = w * 32 + q * 8 + sr8;                                               \
      size_t goff = (size_t)nrow[q] * 512 + (KC) * 64 + sb * 8;                     \
      uint4 u0 = *reinterpret_cast<const uint4*>(p0 + goff);                        \
      uint4 u1 = *reinterpret_cast<const uint4*>(p1 + goff);                        \
      uint4 o4;                                                                     \
      unsigned* a0 = reinterpret_cast<unsigned*>(&u0);                              \
      unsigned* a1 = reinterpret_cast<unsigned*>(&u1);                              \
      unsigned* od = reinterpret_cast<unsigned*>(&o4);                              \
      _Pragma("unroll")                                                             \
      for (int j = 0; j < 4; ++j) {                                                 \
        float lo = bf2f((unsigned short)(a0[j] & 0xffffu)) * w0[q]                  \
                 + bf2f((unsigned short)(a1[j] & 0xffffu)) * w1[q];                 \
        float hi = bf2f((unsigned short)(a0[j] >> 16)) * w0[q]                      \
                 + bf2f((unsigned short)(a1[j] >> 16)) * w1[q];                     \
        od[j] = (unsigned)f2bf(lo) | ((unsigned)f2bf(hi) << 16);                    \
      }                                                                             \
      *reinterpret_cast<uint4*>(&Bl[pb][row * 68 + sb * 8]) = o4;                   \
    }                                                                               \
  } while (0)

  STAGE_A(0);
  STAGE_B(0);
  __syncthreads();
  for (int kc = 0; kc < 8; ++kc) {
    if (kc < 7) { STAGE_A(kc + 1); STAGE_B(kc + 1); }
    const unsigned short* Ac = Al[kc & 1];
    const unsigned short* Bc = Bl[kc & 1];
    #pragma unroll
    for (int kk = 0; kk < 2; ++kk) {
      bf16x8 af[4];
      #pragma unroll
      for (int mt = 0; mt < 4; ++mt)
        af[mt] = *reinterpret_cast<const bf16x8*>(
            &Ac[(mw + mt * 16 + l15) * 64 + (((kk * 4 + quad) ^ (l15 & 7)) << 3)]);
      #pragma unroll
      for (int nt = 0; nt < 4; ++nt) {
        bf16x8 bfr = *reinterpret_cast<const bf16x8*>(
            &Bc[(nw + nt * 16 + l15) * 68 + ((kk * 4 + quad) << 3)]);
        #pragma unroll
        for (int mt = 0; mt < 4; ++mt)
          acc[mt][nt] = __builtin_amdgcn_mfma_f32_16x16x32_bf16(af[mt], bfr, acc[mt][nt], 0, 0, 0);
      }
    }
    __syncthreads();
  }
  #undef STAGE_A
  #undef STAGE_B
  #pragma unroll
  for (int mt = 0; mt < 4; ++mt)
    #pragma unroll
    for (int nt = 0; nt < 4; ++nt)
      #pragma unroll
      for (int rr = 0; rr < 4; ++rr) {
        int row = m0 + mw + mt * 16 + quad * 4 + rr;
        int col = n0 + nw + nt * 16 + l15;
        size_t idx = (size_t)z * (C_ * HW_) + (size_t)row * HW_ + col;
        out[idx] = acc[mt][nt][rr] + bias[row] + resid[idx];
      }
}

// ------- flash attention (r10-verified form, 139.5 us; default block mapping —
// r14's XCD remap cut FETCH 69.7->24.7MB but cost 5%: staging latency is NOT on the
// critical path; kernel is LDS-throughput + barrier bound): Br=64, Bc=256; async DMA +
// XOR swizzle, 2 rotating buffers, depth-1 prefetch, __syncthreads barriers, setprio.
__global__ __launch_bounds__(512, 2) void attn(
    const unsigned short* __restrict__ qg, const unsigned short* __restrict__ kg,
    const unsigned short* __restrict__ vg,  // vT: (b, c, n)
    unsigned short* __restrict__ opart, float* __restrict__ mpart, float* __restrict__ lpart) {
  __shared__ unsigned short KVb[2 * 16384];   // 2 x 32KB chunk buffers (128 rows x 128 cols)
  __shared__ unsigned short Pl[64 * 264];     // 33792 B
  __shared__ float sm_m[64], sm_l[64], sm_alpha[64], sm_red[128];
  int qt = blockIdx.x, jh = blockIdx.y, b = blockIdx.z;
  int t = threadIdx.x, lane = t & 63, w = t >> 6;
  int l15 = lane & 15, quad = lane >> 4;
  int l31 = lane & 31, hl = lane >> 5;
  int rw = w & 3, cw = w >> 2;      // S phase: 4 row-groups(16) x 2 col-halves
  int rw2 = w & 1, dg = w >> 1;     // PV phase: 2 row-groups(32) x 4 d-slots
  int m0 = qt * 64;
  if (t < 64) { sm_m[t] = NEG_INF_; sm_l[t] = 0.f; }

  // staging geometry: thread stages 4 x 16B; wave w covers 1KB blocks w*4+q (4 rows each)
  int st_r[4], st_kb[4];
  #pragma unroll
  for (int q = 0; q < 4; ++q) {
    int blk = w * 4 + q;
    st_r[q] = blk * 4 + (lane >> 4);          // row 0..127 within chunk
    st_kb[q] = (lane & 15) ^ (st_r[q] & 7);   // logical 16B block (col/8)
  }

  #define STAGE_K(JC, KC, J0) do {                                                  \
    const unsigned short* gb = kg + ((size_t)(b * HW_ + (J0) + (JC) * 128)) * K_ + (KC) * 128; \
    unsigned short* lb = KVb + ((((JC) * 4 + (KC)) & 1) << 14);                     \
    _Pragma("unroll")                                                               \
    for (int q = 0; q < 4; ++q)                                                     \
      gld_lds16(gb + (size_t)st_r[q] * K_ + st_kb[q] * 8, lb + (w * 4 + q) * 512);  \
  } while (0)

  // chunk index in PV = jc*4 + dc -> buffer parity = dc&1
  #define STAGE_V(DC, JC, J0) do {                                                 \
    const unsigned short* gb = vg + ((size_t)(b * K_ + (DC) * 128)) * HW_ + (J0) + (JC) * 128; \
    unsigned short* lb = KVb + (((DC) & 1) << 14);                                  \
    _Pragma("unroll")                                                               \
    for (int q = 0; q < 4; ++q)                                                     \
      gld_lds16(gb + (size_t)st_r[q] * HW_ + st_kb[q] * 8, lb + (w * 4 + q) * 512); \
  } while (0)

  bf16x8 qa[16];
  {
    const unsigned short* qrow = qg + ((size_t)(b * HW_ + m0 + rw * 16 + l15)) * K_ + quad * 8;
    #pragma unroll
    for (int kk = 0; kk < 16; ++kk)
      qa[kk] = *reinterpret_cast<const bf16x8*>(qrow + kk * 32);
  }
  f32x16 acc_o[4] = {};    // [dc]: d = dc*128 + dg*32 + l31

  int j0 = jh * 2048;
  STAGE_K(0, 0, j0);       // chunk 0 in flight
  __syncthreads();         // drains chunk 0; publishes sm init

  for (int it = 0; it < 8; ++it, j0 += 256) {
    f32x4 acc_s[8] = {};
    // ===== S phases: 8 chunks (jc 0..1) x (kc 0..3) =====
    #pragma unroll
    for (int c = 0; c < 8; ++c) {
      int jc = c >> 2, kc = c & 3;
      if (c < 7) { STAGE_K((c + 1) >> 2, (c + 1) & 3, j0); }
      else       { STAGE_V(0, 0, j0); }   // PV chunk 0 (parity 0)
      const unsigned short* bufc = KVb + ((c & 1) << 14);
      __builtin_amdgcn_s_setprio(1);
      #pragma unroll
      for (int kk = 0; kk < 4; ++kk)
        #pragma unroll
        for (int ct = 0; ct < 4; ++ct) {
          int jr = cw * 64 + ct * 16 + l15;
          bf16x8 bfr = *reinterpret_cast<const bf16x8*>(
              &bufc[jr * 128 + (((kk * 4 + quad) ^ (l15 & 7)) << 3)]);
          acc_s[jc * 4 + ct] = __builtin_amdgcn_mfma_f32_16x16x32_bf16(qa[kc * 4 + kk], bfr, acc_s[jc * 4 + ct], 0, 0, 0);
        }
      __builtin_amdgcn_s_setprio(0);
      __syncthreads();
    }
    // ===== softmax =====
    float mx[4];
    #pragma unroll
    for (int rr = 0; rr < 4; ++rr) {
      float m = NEG_INF_;
      #pragma unroll
      for (int s = 0; s < 8; ++s) {
        acc_s[s][rr] *= SCALE_;
        m = fmaxf(m, acc_s[s][rr]);
      }
      mx[rr] = m;
    }
    #pragma unroll
    for (int off = 1; off < 16; off <<= 1)
      #pragma unroll
      for (int rr = 0; rr < 4; ++rr)
        mx[rr] = fmaxf(mx[rr], __shfl_xor(mx[rr], off));
    if (l15 == 0)
      #pragma unroll
      for (int rr = 0; rr < 4; ++rr)
        sm_red[cw * 64 + rw * 16 + quad * 4 + rr] = mx[rr];
    __syncthreads();
    if (t < 64) {
      float mnew = fmaxf(sm_m[t], fmaxf(sm_red[t], sm_red[64 + t]));
      sm_alpha[t] = __expf(sm_m[t] - mnew);
      sm_m[t] = mnew;
    }
    __syncthreads();
    float sum[4] = {0.f, 0.f, 0.f, 0.f};
    #pragma unroll
    for (int s = 0; s < 8; ++s)
      #pragma unroll
      for (int rr = 0; rr < 4; ++rr) {
        int rowl = rw * 16 + quad * 4 + rr;
        float p = __expf(acc_s[s][rr] - sm_m[rowl]);
        sum[rr] += p;
        Pl[rowl * 264 + (s >> 2) * 128 + cw * 64 + (s & 3) * 16 + l15] = f2bf(p);
      }
    #pragma unroll
    for (int off = 1; off < 16; off <<= 1)
      #pragma unroll
      for (int rr = 0; rr < 4; ++rr)
        sum[rr] += __shfl_xor(sum[rr], off);
    if (l15 == 0)
      #pragma unroll
      for (int rr = 0; rr < 4; ++rr)
        sm_red[cw * 64 + rw * 16 + quad * 4 + rr] = sum[rr];
    __syncthreads();
    if (t < 64)
      sm_l[t] = sm_l[t] * sm_alpha[t] + sm_red[t] + sm_red[64 + t];
    // rescale O by alpha (32x32 C/D row mapping)
    #pragma unroll
    for (int r16 = 0; r16 < 16; ++r16) {
      int row = rw2 * 32 + (r16 & 3) + 8 * (r16 >> 2) + 4 * hl;
      float a = sm_alpha[row];
      #pragma unroll
      for (int dc = 0; dc < 4; ++dc)
        acc_o[dc][r16] *= a;
    }
    // ===== PV phases: 8 chunks, dc-inner (c: jc=c>>2, dc=c&3); pa_r reused across dc =====
    bf16x8 pa_r[8];
    #pragma unroll
    for (int c = 0; c < 8; ++c) {
      int jc = c >> 2, dc = c & 3;
      if ((c & 3) == 0) {
        #pragma unroll
        for (int ksx = 0; ksx < 8; ++ksx)
          pa_r[ksx] = *reinterpret_cast<const bf16x8*>(
              &Pl[(rw2 * 32 + l31) * 264 + jc * 128 + ksx * 16 + hl * 8]);
      }
      if (c < 7)          { STAGE_V((c + 1) & 3, (c + 1) >> 2, j0); }
      else if (it < 7)    { STAGE_K(0, 0, j0 + 256); }
      const unsigned short* bufc = KVb + ((c & 1) << 14);
      __builtin_amdgcn_s_setprio(1);
      #pragma unroll
      for (int ksx = 0; ksx < 8; ++ksx) {
        bf16x8 vb = *reinterpret_cast<const bf16x8*>(
            &bufc[(dg * 32 + l31) * 128 + (((ksx * 2 + hl) ^ (l31 & 7)) << 3)]);
        acc_o[dc] = __builtin_amdgcn_mfma_f32_32x32x16_bf16(pa_r[ksx], vb, acc_o[dc], 0, 0, 0);
      }
      __builtin_amdgcn_s_setprio(0);
      __syncthreads();
    }
  }
  #undef STAGE_K
  #undef STAGE_V
  // write partials (unnormalized O in bf16, running m and l)
  int part = jh * 2 + b;
  unsigned short* ob = opart + ((size_t)part * HW_ + m0) * 512;
  #pragma unroll
  for (int dc = 0; dc < 4; ++dc) {
    int d = dc * 128 + dg * 32 + l31;
    #pragma unroll
    for (int r16 = 0; r16 < 16; ++r16) {
      int row = rw2 * 32 + (r16 & 3) + 8 * (r16 >> 2) + 4 * hl;
      ob[(size_t)row * 512 + d] = f2bf(acc_o[dc][r16]);
    }
  }
  if (t < 64) {
    mpart[(size_t)part * HW_ + m0 + t] = sm_m[t];
    lpart[(size_t)part * HW_ + m0 + t] = sm_l[t];
  }
}

extern "C" void kernel_launch(void* const* d_in, const int* in_sizes, int n_in,
                              void* d_out, int out_size, void* d_ws, size_t ws_size,
                              hipStream_t stream) {
  const float* x     = (const float*)d_in[0];
  const float* gamma = (const float*)d_in[1];
  const float* beta  = (const float*)d_in[2];
  const float* wq    = (const float*)d_in[3];
  const float* bq    = (const float*)d_in[4];
  const float* wk    = (const float*)d_in[5];
  const float* bk    = (const float*)d_in[6];
  const float* wv    = (const float*)d_in[7];
  const float* bv    = (const float*)d_in[8];
  const float* wp    = (const float*)d_in[9];
  const float* bp    = (const float*)d_in[10];
  float* out = (float*)d_out;

  char* ws = (char*)d_ws;
  size_t o = 0;
  float* pstats         = (float*)(ws + o);          o += 8192;      // 2048 f32 partials
  unsigned short* tb    = (unsigned short*)(ws + o); o += 8388608;
  unsigned short* qb    = (unsigned short*)(ws + o); o += 8388608;
  unsigned short* kb    = (unsigned short*)(ws + o); o += 8388608;
  unsigned short* vTb   = (unsigned short*)(ws + o); o += 8388608;
  unsigned short* wqb   = (unsigned short*)(ws + o); o += 524288;
  unsigned short* wkb   = (unsigned short*)(ws + o); o += 524288;
  unsigned short* wvb   = (unsigned short*)(ws + o); o += 524288;
  unsigned short* wpb   = (unsigned short*)(ws + o); o += 524288;
  unsigned short* opart = (unsigned short*)(ws + o); o += 16777216;  // 4 parts bf16
  float* mpart          = (float*)(ws + o);          o += 65536;
  float* lpart          = (float*)(ws + o);          o += 65536;

  // fused groupnorm partial sums + weight cast (no memset, no atomics)
  gn_cast<<<2048, 256, 0, stream>>>(x, pstats, wq, wk, wv, wp, wqb);
  build_t<<<dim3(64, 8, 2), 256, 0, stream>>>(x, pstats, gamma, beta, tb);
  // fused q,k,vT projections (XCD-grouped)
  gemm_qkv<<<dim3(4, 32, 6), 256, 0, stream>>>(tb, wqb, bq, bk, bv, qb, kb, vTb);
  attn<<<dim3(64, 2, 2), 512, 0, stream>>>(qb, kb, vTb, opart, mpart, lpart);
  // final projection with fused partial-merge + residual
  gemm_fin<<<dim3(32, 4, 2), 256, 0, stream>>>(wpb, opart, mpart, lpart, bp, x, out);
}

// Round 9
// 259.235 us; speedup vs baseline: 1.0411x; 1.0222x over previous
//
#include <hip/hip_runtime.h>
#include <hip/hip_bf16.h>

#define B_ 2
#define C_ 512
#define HW_ 4096
#define K_ 512
#define EPS_ 1e-6f
#define SCALE_ 0.04419417382415922f   // 512^-0.5
#define NEG_INF_ (-1e30f)

typedef __attribute__((ext_vector_type(8))) __bf16 bf16x8;
typedef __attribute__((ext_vector_type(4))) float f32x4;
typedef __attribute__((ext_vector_type(16))) float f32x16;

__device__ __forceinline__ unsigned short f2bf(float f) {
  union { float f; unsigned u; } v; v.f = f;
  unsigned r = v.u + 0x7fffu + ((v.u >> 16) & 1u);
  return (unsigned short)(r >> 16);
}
__device__ __forceinline__ float bf2f(unsigned short h) {
  union { unsigned u; float f; } v; v.u = ((unsigned)h) << 16;
  return v.f;
}

// direct global->LDS DMA, 16B per lane. LDS dst = wave-uniform base + lane*16.
__device__ __forceinline__ void gld_lds16(const unsigned short* g, unsigned short* l) {
  __builtin_amdgcn_global_load_lds((const __attribute__((address_space(1))) void*)g,
                                   (__attribute__((address_space(3))) void*)l, 16, 0, 0);
}

// ------- fused: GroupNorm partial sums (blocks 0..1023, no atomics/memset)
//         + f32->bf16 weight cast (blocks 1024..2047) -------
// pstats[bid] = sum, pstats[1024+bid] = sumsq  (bid = bg*16 + rowblk)
__global__ void gn_cast(const float* __restrict__ x, float* __restrict__ pstats,
                        const float* __restrict__ s0, const float* __restrict__ s1,
                        const float* __restrict__ s2, const float* __restrict__ s3,
                        unsigned short* __restrict__ dst) {
  int bid = blockIdx.x;
  int t = threadIdx.x;
  if (bid < 1024) {
    int bg = bid >> 4, row = bid & 15;
    int b = bg >> 5, g = bg & 31;
    const float* base = x + ((size_t)(b * C_ + g * 16 + row)) * HW_;
    float s = 0.f, s2 = 0.f;
    #pragma unroll
    for (int i = 0; i < 4; ++i) {
      float4 v = *reinterpret_cast<const float4*>(base + (size_t)(t + i * 256) * 4);
      s  += v.x + v.y + v.z + v.w;
      s2 += v.x * v.x + v.y * v.y + v.z * v.z + v.w * v.w;
    }
    for (int off = 32; off; off >>= 1) { s += __shfl_down(s, off); s2 += __shfl_down(s2, off); }
    __shared__ float rs[4], rs2[4];
    int w = t >> 6;
    if ((t & 63) == 0) { rs[w] = s; rs2[w] = s2; }
    __syncthreads();
    if (t == 0) {
      pstats[bid] = rs[0] + rs[1] + rs[2] + rs[3];
      pstats[1024 + bid] = rs2[0] + rs2[1] + rs2[2] + rs2[3];
    }
  } else {
    int cid = bid - 1024;
    int which = cid >> 8, bx = cid & 255;
    const float* src = which == 0 ? s0 : which == 1 ? s1 : which == 2 ? s2 : s3;
    int i = (bx * 256 + t) * 4;
    float4 v = *reinterpret_cast<const float4*>(src + i);
    ushort4 o; o.x = f2bf(v.x); o.y = f2bf(v.y); o.z = f2bf(v.z); o.w = f2bf(v.w);
    *reinterpret_cast<ushort4*>(dst + (size_t)which * 262144 + i) = o;
  }
}

// ------------- normalize + transpose: x(b,c,n) f32 -> t(b,n,c) bf16 -------------
// reduces the 16 per-rowblock partials inline (L2-hot)
__global__ void build_t(const float* __restrict__ x, const float* __restrict__ pstats,
                        const float* __restrict__ gamma, const float* __restrict__ beta,
                        unsigned short* __restrict__ tb) {
  __shared__ float lds[64 * 69];
  int n0 = blockIdx.x * 64, c0 = blockIdx.y * 64, b = blockIdx.z;
  int t = threadIdx.x;
  {
    int cl = t >> 2, ch = t & 3;
    int c = c0 + cl;
    int bg = b * 32 + (c >> 4);
    float s = 0.f, s2v = 0.f;
    #pragma unroll
    for (int r = 0; r < 16; ++r) {
      s   += pstats[bg * 16 + r];
      s2v += pstats[1024 + bg * 16 + r];
    }
    float mean = s * (1.f / 65536.f);
    float var = s2v * (1.f / 65536.f) - mean * mean;
    float rstd = rsqrtf(var + EPS_);
    float ga = gamma[c] * rstd;
    float be = beta[c] - mean * ga;
    const float* xr = x + ((size_t)(b * C_ + c)) * HW_ + n0 + ch * 16;
    #pragma unroll
    for (int i = 0; i < 4; ++i) {
      float4 v = *reinterpret_cast<const float4*>(xr + i * 4);
      int nl = ch * 16 + i * 4;
      lds[cl * 69 + nl + 0] = v.x * ga + be;
      lds[cl * 69 + nl + 1] = v.y * ga + be;
      lds[cl * 69 + nl + 2] = v.z * ga + be;
      lds[cl * 69 + nl + 3] = v.w * ga + be;
    }
  }
  __syncthreads();
  {
    int nl = t >> 2, cw = t & 3;
    unsigned short* orow = tb + ((size_t)(b * HW_ + n0 + nl)) * C_ + c0 + cw * 16;
    #pragma unroll
    for (int i = 0; i < 4; ++i) {
      ushort4 o4;
      o4.x = f2bf(lds[(cw * 16 + i * 4 + 0) * 69 + nl]);
      o4.y = f2bf(lds[(cw * 16 + i * 4 + 1) * 69 + nl]);
      o4.z = f2bf(lds[(cw * 16 + i * 4 + 2) * 69 + nl]);
      o4.w = f2bf(lds[(cw * 16 + i * 4 + 3) * 69 + nl]);
      *reinterpret_cast<ushort4*>(orow + i * 4) = o4;
    }
  }
}

// ---------------- fused Q/K/V^T projections, one launch ----------------
// z = which*2 + b; which 0: q = t.wq^T (bias/col), 1: k (bias/col), 2: vT = wv.t^T (bias/row)
// XCD-aware remap: the 4 n-blocks sharing one t-tile land on the SAME XCD (T1),
// so the shared A/B t-operand is fetched into one L2, not four. (r14: ~5 us win)
__global__ __launch_bounds__(256, 2) void gemm_qkv(
    const unsigned short* __restrict__ tb, const unsigned short* __restrict__ wqkv,
    const float* __restrict__ bq, const float* __restrict__ bk, const float* __restrict__ bv,
    unsigned short* __restrict__ qb, unsigned short* __restrict__ kb,
    unsigned short* __restrict__ vTb) {
  __shared__ unsigned short Al[2][128 * 64];
  __shared__ unsigned short Bl[2][128 * 64];
  // bijective remap of 768 blocks: xcd = f&7 fixed; i>>2 selects (y,z) combo, i&3 the x
  int f = blockIdx.x + 4 * (blockIdx.y + 32 * blockIdx.z);
  int xcd = f & 7, i = f >> 3;
  int bx = i & 3;
  int g = xcd * 24 + (i >> 2);     // 0..191
  int bz = g >> 5, by = g & 31;
  int which = bz >> 1, b = bz & 1;
  const unsigned short* Ab = (which < 2) ? (tb + (size_t)b * HW_ * K_) : (wqkv + 2 * 262144);
  const unsigned short* Bb = (which < 2) ? (wqkv + which * 262144) : (tb + (size_t)b * HW_ * K_);
  int m0 = (which < 2) ? by * 128 : bx * 128;
  int n0 = (which < 2) ? bx * 128 : by * 128;
  int N = (which < 2) ? 512 : HW_;
  unsigned short* Cb = (which == 0) ? (qb + (size_t)b * HW_ * K_)
                     : (which == 1) ? (kb + (size_t)b * HW_ * K_)
                                    : (vTb + (size_t)b * C_ * HW_);
  const float* bias = (which == 0) ? bq : (which == 1) ? bk : bv;
  int t = threadIdx.x, lane = t & 63, w = t >> 6;
  int l15 = lane & 15, quad = lane >> 4;
  int mw = (w & 1) * 64, nw = (w >> 1) * 64;
  int sr8 = lane >> 3, sb = lane & 7;
  f32x4 acc[4][4] = {};

  #define G_STAGE(KC) do {                                                          \
    int pb = (KC) & 1;                                                              \
    _Pragma("unroll")                                                               \
    for (int q = 0; q < 4; ++q) {                                                   \
      int row = w * 32 + q * 8 + sr8;                                               \
      int gb = sb ^ (row & 7);                                                      \
      gld_lds16(Ab + (size_t)(m0 + row) * K_ + (KC) * 64 + gb * 8, &Al[pb][(w * 32 + q * 8) * 64]); \
      gld_lds16(Bb + (size_t)(n0 + row) * K_ + (KC) * 64 + gb * 8, &Bl[pb][(w * 32 + q * 8) * 64]); \
    }                                                                               \
  } while (0)

  G_STAGE(0);
  __syncthreads();
  for (int kc = 0; kc < 8; ++kc) {
    if (kc < 7) G_STAGE(kc + 1);
    const unsigned short* Ac = Al[kc & 1];
    const unsigned short* Bc = Bl[kc & 1];
    #pragma unroll
    for (int kk = 0; kk < 2; ++kk) {
      bf16x8 af[4];
      #pragma unroll
      for (int mt = 0; mt < 4; ++mt)
        af[mt] = *reinterpret_cast<const bf16x8*>(
            &Ac[(mw + mt * 16 + l15) * 64 + (((kk * 4 + quad) ^ (l15 & 7)) << 3)]);
      #pragma unroll
      for (int nt = 0; nt < 4; ++nt) {
        bf16x8 bfr = *reinterpret_cast<const bf16x8*>(
            &Bc[(nw + nt * 16 + l15) * 64 + (((kk * 4 + quad) ^ (l15 & 7)) << 3)]);
        #pragma unroll
        for (int mt = 0; mt < 4; ++mt)
          acc[mt][nt] = __builtin_amdgcn_mfma_f32_16x16x32_bf16(af[mt], bfr, acc[mt][nt], 0, 0, 0);
      }
    }
    __syncthreads();
  }
  #undef G_STAGE
  #pragma unroll
  for (int mt = 0; mt < 4; ++mt)
    #pragma unroll
    for (int nt = 0; nt < 4; ++nt)
      #pragma unroll
      for (int rr = 0; rr < 4; ++rr) {
        int row = m0 + mw + mt * 16 + quad * 4 + rr;
        int col = n0 + nw + nt * 16 + l15;
        float v = acc[mt][nt][rr] + ((which < 2) ? bias[col] : bias[row]);
        Cb[(size_t)row * N + col] = f2bf(v);
      }
}

// ---------------- final projection + residual, with fused opart merge ----------------
// out[z][m][n] = x[z][m][n] + bp[m] + wp[m] . merged_o[z][n]
// r16: 128x64 tiles -> 512 blocks -> 2 blocks/CU co-resident (was 256 blocks = 1/CU solo;
// solo blocks eat every barrier drain with no partner wave to overlap). 2m x 2n waves.
__global__ __launch_bounds__(256, 2) void gemm_fin(
    const unsigned short* __restrict__ A,            // wpb 512x512 bf16
    const unsigned short* __restrict__ opart,        // 4 parts (jh*2+z)
    const float* __restrict__ mpart, const float* __restrict__ lpart,
    const float* __restrict__ bias, const float* __restrict__ resid,
    float* __restrict__ out) {
  __shared__ unsigned short Al[2][128 * 64];
  __shared__ unsigned short Bl[2][64 * 68];    // padded: row stride 68 shorts
  int z = blockIdx.z;
  int n0 = blockIdx.x * 64, m0 = blockIdx.y * 128;
  int t = threadIdx.x, lane = t & 63, w = t >> 6;
  int l15 = lane & 15, quad = lane >> 4;
  int mw = (w & 1) * 64, nw = (w >> 1) * 32;   // 2 m-waves(64) x 2 n-waves(32)
  int sr8 = lane >> 3, sb = lane & 7;
  f32x4 acc[4][2] = {};

  // per-thread merge weights for the 2 B-rows it stages
  float w0[2], w1[2];
  int nrow[2];
  #pragma unroll
  for (int q = 0; q < 2; ++q) {
    int n = n0 + w * 16 + q * 8 + sr8;
    nrow[q] = n;
    float ma = mpart[(size_t)z * HW_ + n], mb = mpart[(size_t)(2 + z) * HW_ + n];
    float la = lpart[(size_t)z * HW_ + n], lb = lpart[(size_t)(2 + z) * HW_ + n];
    float M = fmaxf(ma, mb);
    float ea = __expf(ma - M), eb = __expf(mb - M);
    float iv = 1.f / (la * ea + lb * eb);
    w0[q] = ea * iv; w1[q] = eb * iv;
  }
  const unsigned short* p0 = opart + (size_t)z * HW_ * 512;
  const unsigned short* p1 = opart + (size_t)(2 + z) * HW_ * 512;

  #define STAGE_A(KC) do {                                                          \
    int pb = (KC) & 1;                                                              \
    _Pragma("unroll")                                                               \
    for (int q = 0; q < 4; ++q) {                                                   \
      int row = w * 32 + q * 8 + sr8;                                               \
      int gb = sb ^ (row & 7);                                                      \
      gld_lds16(A + (size_t)(m0 + row) * K_ + (KC) * 64 + gb * 8, &Al[pb][(w * 32 + q * 8) * 64]); \
    }                                                                               \
  } while (0)

  #define STAGE_B(KC) do {                                                          \
    int pb = (KC) & 1;                                                              \
    _Pragma("unroll")                                                               \
    for (int q = 0; q < 2; ++q) {                                                   \
      int row = w * 16 + q * 8 + sr8;                                               \
      size_t goff = (size_t)nrow[q] * 512 + (KC) * 64 + sb * 8;                     \
      uint4 u0 = *reinterpret_cast<const uint4*>(p0 + goff);                        \
      uint4 u1 = *reinterpret_cast<const uint4*>(p1 + goff);                        \
      uint4 o4;                                                                     \
      unsigned* a0 = reinterpret_cast<unsigned*>(&u0);                              \
      unsigned* a1 = reinterpret_cast<unsigned*>(&u1);                              \
      unsigned* od = reinterpret_cast<unsigned*>(&o4);                              \
      _Pragma("unroll")                                                             \
      for (int j = 0; j < 4; ++j) {                                                 \
        float lo = bf2f((unsigned short)(a0[j] & 0xffffu)) * w0[q]                  \
                 + bf2f((unsigned short)(a1[j] & 0xffffu)) * w1[q];                 \
        float hi = bf2f((unsigned short)(a0[j] >> 16)) * w0[q]                      \
                 + bf2f((unsigned short)(a1[j] >> 16)) * w1[q];                     \
        od[j] = (unsigned)f2bf(lo) | ((unsigned)f2bf(hi) << 16);                    \
      }                                                                             \
      *reinterpret_cast<uint4*>(&Bl[pb][row * 68 + sb * 8]) = o4;                   \
    }                                                                               \
  } while (0)

  STAGE_A(0);
  STAGE_B(0);
  __syncthreads();
  for (int kc = 0; kc < 8; ++kc) {
    if (kc < 7) { STAGE_A(kc + 1); STAGE_B(kc + 1); }
    const unsigned short* Ac = Al[kc & 1];
    const unsigned short* Bc = Bl[kc & 1];
    #pragma unroll
    for (int kk = 0; kk < 2; ++kk) {
      bf16x8 af[4];
      #pragma unroll
      for (int mt = 0; mt < 4; ++mt)
        af[mt] = *reinterpret_cast<const bf16x8*>(
            &Ac[(mw + mt * 16 + l15) * 64 + (((kk * 4 + quad) ^ (l15 & 7)) << 3)]);
      #pragma unroll
      for (int nt = 0; nt < 2; ++nt) {
        bf16x8 bfr = *reinterpret_cast<const bf16x8*>(
            &Bc[(nw + nt * 16 + l15) * 68 + ((kk * 4 + quad) << 3)]);
        #pragma unroll
        for (int mt = 0; mt < 4; ++mt)
          acc[mt][nt] = __builtin_amdgcn_mfma_f32_16x16x32_bf16(af[mt], bfr, acc[mt][nt], 0, 0, 0);
      }
    }
    __syncthreads();
  }
  #undef STAGE_A
  #undef STAGE_B
  #pragma unroll
  for (int mt = 0; mt < 4; ++mt)
    #pragma unroll
    for (int nt = 0; nt < 2; ++nt)
      #pragma unroll
      for (int rr = 0; rr < 4; ++rr) {
        int row = m0 + mw + mt * 16 + quad * 4 + rr;
        int col = n0 + nw + nt * 16 + l15;
        size_t idx = (size_t)z * (C_ * HW_) + (size_t)row * HW_ + col;
        out[idx] = acc[mt][nt][rr] + bias[row] + resid[idx];
      }
}

// ------- flash attention (r10-verified form, 139.5 us; default block mapping —
// r14's XCD remap cut FETCH 69.7->24.7MB but cost 5%: staging latency is NOT on the
// critical path; kernel is LDS-throughput + barrier bound): Br=64, Bc=256; async DMA +
// XOR swizzle, 2 rotating buffers, depth-1 prefetch, __syncthreads barriers, setprio.
__global__ __launch_bounds__(512, 2) void attn(
    const unsigned short* __restrict__ qg, const unsigned short* __restrict__ kg,
    const unsigned short* __restrict__ vg,  // vT: (b, c, n)
    unsigned short* __restrict__ opart, float* __restrict__ mpart, float* __restrict__ lpart) {
  __shared__ unsigned short KVb[2 * 16384];   // 2 x 32KB chunk buffers (128 rows x 128 cols)
  __shared__ unsigned short Pl[64 * 264];     // 33792 B
  __shared__ float sm_m[64], sm_l[64], sm_alpha[64], sm_red[128];
  int qt = blockIdx.x, jh = blockIdx.y, b = blockIdx.z;
  int t = threadIdx.x, lane = t & 63, w = t >> 6;
  int l15 = lane & 15, quad = lane >> 4;
  int l31 = lane & 31, hl = lane >> 5;
  int rw = w & 3, cw = w >> 2;      // S phase: 4 row-groups(16) x 2 col-halves
  int rw2 = w & 1, dg = w >> 1;     // PV phase: 2 row-groups(32) x 4 d-slots
  int m0 = qt * 64;
  if (t < 64) { sm_m[t] = NEG_INF_; sm_l[t] = 0.f; }

  // staging geometry: thread stages 4 x 16B; wave w covers 1KB blocks w*4+q (4 rows each)
  int st_r[4], st_kb[4];
  #pragma unroll
  for (int q = 0; q < 4; ++q) {
    int blk = w * 4 + q;
    st_r[q] = blk * 4 + (lane >> 4);          // row 0..127 within chunk
    st_kb[q] = (lane & 15) ^ (st_r[q] & 7);   // logical 16B block (col/8)
  }

  #define STAGE_K(JC, KC, J0) do {                                                  \
    const unsigned short* gb = kg + ((size_t)(b * HW_ + (J0) + (JC) * 128)) * K_ + (KC) * 128; \
    unsigned short* lb = KVb + ((((JC) * 4 + (KC)) & 1) << 14);                     \
    _Pragma("unroll")                                                               \
    for (int q = 0; q < 4; ++q)                                                     \
      gld_lds16(gb + (size_t)st_r[q] * K_ + st_kb[q] * 8, lb + (w * 4 + q) * 512);  \
  } while (0)

  // chunk index in PV = jc*4 + dc -> buffer parity = dc&1
  #define STAGE_V(DC, JC, J0) do {                                                 \
    const unsigned short* gb = vg + ((size_t)(b * K_ + (DC) * 128)) * HW_ + (J0) + (JC) * 128; \
    unsigned short* lb = KVb + (((DC) & 1) << 14);                                  \
    _Pragma("unroll")                                                               \
    for (int q = 0; q < 4; ++q)                                                     \
      gld_lds16(gb + (size_t)st_r[q] * HW_ + st_kb[q] * 8, lb + (w * 4 + q) * 512); \
  } while (0)

  bf16x8 qa[16];
  {
    const unsigned short* qrow = qg + ((size_t)(b * HW_ + m0 + rw * 16 + l15)) * K_ + quad * 8;
    #pragma unroll
    for (int kk = 0; kk < 16; ++kk)
      qa[kk] = *reinterpret_cast<const bf16x8*>(qrow + kk * 32);
  }
  f32x16 acc_o[4] = {};    // [dc]: d = dc*128 + dg*32 + l31

  int j0 = jh * 2048;
  STAGE_K(0, 0, j0);       // chunk 0 in flight
  __syncthreads();         // drains chunk 0; publishes sm init

  for (int it = 0; it < 8; ++it, j0 += 256) {
    f32x4 acc_s[8] = {};
    // ===== S phases: 8 chunks (jc 0..1) x (kc 0..3) =====
    #pragma unroll
    for (int c = 0; c < 8; ++c) {
      int jc = c >> 2, kc = c & 3;
      if (c < 7) { STAGE_K((c + 1) >> 2, (c + 1) & 3, j0); }
      else       { STAGE_V(0, 0, j0); }   // PV chunk 0 (parity 0)
      const unsigned short* bufc = KVb + ((c & 1) << 14);
      __builtin_amdgcn_s_setprio(1);
      #pragma unroll
      for (int kk = 0; kk < 4; ++kk)
        #pragma unroll
        for (int ct = 0; ct < 4; ++ct) {
          int jr = cw * 64 + ct * 16 + l15;
          bf16x8 bfr = *reinterpret_cast<const bf16x8*>(
              &bufc[jr * 128 + (((kk * 4 + quad) ^ (l15 & 7)) << 3)]);
          acc_s[jc * 4 + ct] = __builtin_amdgcn_mfma_f32_16x16x32_bf16(qa[kc * 4 + kk], bfr, acc_s[jc * 4 + ct], 0, 0, 0);
        }
      __builtin_amdgcn_s_setprio(0);
      __syncthreads();
    }
    // ===== softmax =====
    float mx[4];
    #pragma unroll
    for (int rr = 0; rr < 4; ++rr) {
      float m = NEG_INF_;
      #pragma unroll
      for (int s = 0; s < 8; ++s) {
        acc_s[s][rr] *= SCALE_;
        m = fmaxf(m, acc_s[s][rr]);
      }
      mx[rr] = m;
    }
    #pragma unroll
    for (int off = 1; off < 16; off <<= 1)
      #pragma unroll
      for (int rr = 0; rr < 4; ++rr)
        mx[rr] = fmaxf(mx[rr], __shfl_xor(mx[rr], off));
    if (l15 == 0)
      #pragma unroll
      for (int rr = 0; rr < 4; ++rr)
        sm_red[cw * 64 + rw * 16 + quad * 4 + rr] = mx[rr];
    __syncthreads();
    if (t < 64) {
      float mnew = fmaxf(sm_m[t], fmaxf(sm_red[t], sm_red[64 + t]));
      sm_alpha[t] = __expf(sm_m[t] - mnew);
      sm_m[t] = mnew;
    }
    __syncthreads();
    float sum[4] = {0.f, 0.f, 0.f, 0.f};
    #pragma unroll
    for (int s = 0; s < 8; ++s)
      #pragma unroll
      for (int rr = 0; rr < 4; ++rr) {
        int rowl = rw * 16 + quad * 4 + rr;
        float p = __expf(acc_s[s][rr] - sm_m[rowl]);
        sum[rr] += p;
        Pl[rowl * 264 + (s >> 2) * 128 + cw * 64 + (s & 3) * 16 + l15] = f2bf(p);
      }
    #pragma unroll
    for (int off = 1; off < 16; off <<= 1)
      #pragma unroll
      for (int rr = 0; rr < 4; ++rr)
        sum[rr] += __shfl_xor(sum[rr], off);
    if (l15 == 0)
      #pragma unroll
      for (int rr = 0; rr < 4; ++rr)
        sm_red[cw * 64 + rw * 16 + quad * 4 + rr] = sum[rr];
    __syncthreads();
    if (t < 64)
      sm_l[t] = sm_l[t] * sm_alpha[t] + sm_red[t] + sm_red[64 + t];
    // rescale O by alpha (32x32 C/D row mapping)
    #pragma unroll
    for (int r16 = 0; r16 < 16; ++r16) {
      int row = rw2 * 32 + (r16 & 3) + 8 * (r16 >> 2) + 4 * hl;
      float a = sm_alpha[row];
      #pragma unroll
      for (int dc = 0; dc < 4; ++dc)
        acc_o[dc][r16] *= a;
    }
    // ===== PV phases: 8 chunks, dc-inner (c: jc=c>>2, dc=c&3); pa_r reused across dc =====
    bf16x8 pa_r[8];
    #pragma unroll
    for (int c = 0; c < 8; ++c) {
      int jc = c >> 2, dc = c & 3;
      if ((c & 3) == 0) {
        #pragma unroll
        for (int ksx = 0; ksx < 8; ++ksx)
          pa_r[ksx] = *reinterpret_cast<const bf16x8*>(
              &Pl[(rw2 * 32 + l31) * 264 + jc * 128 + ksx * 16 + hl * 8]);
      }
      if (c < 7)          { STAGE_V((c + 1) & 3, (c + 1) >> 2, j0); }
      else if (it < 7)    { STAGE_K(0, 0, j0 + 256); }
      const unsigned short* bufc = KVb + ((c & 1) << 14);
      __builtin_amdgcn_s_setprio(1);
      #pragma unroll
      for (int ksx = 0; ksx < 8; ++ksx) {
        bf16x8 vb = *reinterpret_cast<const bf16x8*>(
            &bufc[(dg * 32 + l31) * 128 + (((ksx * 2 + hl) ^ (l31 & 7)) << 3)]);
        acc_o[dc] = __builtin_amdgcn_mfma_f32_32x32x16_bf16(pa_r[ksx], vb, acc_o[dc], 0, 0, 0);
      }
      __builtin_amdgcn_s_setprio(0);
      __syncthreads();
    }
  }
  #undef STAGE_K
  #undef STAGE_V
  // write partials (unnormalized O in bf16, running m and l)
  int part = jh * 2 + b;
  unsigned short* ob = opart + ((size_t)part * HW_ + m0) * 512;
  #pragma unroll
  for (int dc = 0; dc < 4; ++dc) {
    int d = dc * 128 + dg * 32 + l31;
    #pragma unroll
    for (int r16 = 0; r16 < 16; ++r16) {
      int row = rw2 * 32 + (r16 & 3) + 8 * (r16 >> 2) + 4 * hl;
      ob[(size_t)row * 512 + d] = f2bf(acc_o[dc][r16]);
    }
  }
  if (t < 64) {
    mpart[(size_t)part * HW_ + m0 + t] = sm_m[t];
    lpart[(size_t)part * HW_ + m0 + t] = sm_l[t];
  }
}

extern "C" void kernel_launch(void* const* d_in, const int* in_sizes, int n_in,
                              void* d_out, int out_size, void* d_ws, size_t ws_size,
                              hipStream_t stream) {
  const float* x     = (const float*)d_in[0];
  const float* gamma = (const float*)d_in[1];
  const float* beta  = (const float*)d_in[2];
  const float* wq    = (const float*)d_in[3];
  const float* bq    = (const float*)d_in[4];
  const float* wk    = (const float*)d_in[5];
  const float* bk    = (const float*)d_in[6];
  const float* wv    = (const float*)d_in[7];
  const float* bv    = (const float*)d_in[8];
  const float* wp    = (const float*)d_in[9];
  const float* bp    = (const float*)d_in[10];
  float* out = (float*)d_out;

  char* ws = (char*)d_ws;
  size_t o = 0;
  float* pstats         = (float*)(ws + o);          o += 8192;      // 2048 f32 partials
  unsigned short* tb    = (unsigned short*)(ws + o); o += 8388608;
  unsigned short* qb    = (unsigned short*)(ws + o); o += 8388608;
  unsigned short* kb    = (unsigned short*)(ws + o); o += 8388608;
  unsigned short* vTb   = (unsigned short*)(ws + o); o += 8388608;
  unsigned short* wqb   = (unsigned short*)(ws + o); o += 524288;
  unsigned short* wkb   = (unsigned short*)(ws + o); o += 524288;
  unsigned short* wvb   = (unsigned short*)(ws + o); o += 524288;
  unsigned short* wpb   = (unsigned short*)(ws + o); o += 524288;
  unsigned short* opart = (unsigned short*)(ws + o); o += 16777216;  // 4 parts bf16
  float* mpart          = (float*)(ws + o);          o += 65536;
  float* lpart          = (float*)(ws + o);          o += 65536;

  // fused groupnorm partial sums + weight cast (no memset, no atomics)
  gn_cast<<<2048, 256, 0, stream>>>(x, pstats, wq, wk, wv, wp, wqb);
  build_t<<<dim3(64, 8, 2), 256, 0, stream>>>(x, pstats, gamma, beta, tb);
  // fused q,k,vT projections (XCD-grouped)
  gemm_qkv<<<dim3(4, 32, 6), 256, 0, stream>>>(tb, wqb, bq, bk, bv, qb, kb, vTb);
  attn<<<dim3(64, 2, 2), 512, 0, stream>>>(qb, kb, vTb, opart, mpart, lpart);
  // final projection with fused partial-merge + residual (512 blocks -> 2/CU)
  gemm_fin<<<dim3(64, 4, 2), 256, 0, stream>>>(wpb, opart, mpart, lpart, bp, x, out);
}

// Round 10
// 249.525 us; speedup vs baseline: 1.0816x; 1.0389x over previous
//
#include <hip/hip_runtime.h>
#include <hip/hip_bf16.h>

#define B_ 2
#define C_ 512
#define HW_ 4096
#define K_ 512
#define EPS_ 1e-6f
#define SCALE_ 0.04419417382415922f   // 512^-0.5
#define NEG_INF_ (-1e30f)

typedef __attribute__((ext_vector_type(8))) __bf16 bf16x8;
typedef __attribute__((ext_vector_type(4))) float f32x4;
typedef __attribute__((ext_vector_type(16))) float f32x16;

__device__ __forceinline__ unsigned short f2bf(float f) {
  union { float f; unsigned u; } v; v.f = f;
  unsigned r = v.u + 0x7fffu + ((v.u >> 16) & 1u);
  return (unsigned short)(r >> 16);
}
__device__ __forceinline__ float bf2f(unsigned short h) {
  union { unsigned u; float f; } v; v.u = ((unsigned)h) << 16;
  return v.f;
}

// direct global->LDS DMA, 16B per lane. LDS dst = wave-uniform base + lane*16.
__device__ __forceinline__ void gld_lds16(const unsigned short* g, unsigned short* l) {
  __builtin_amdgcn_global_load_lds((const __attribute__((address_space(1))) void*)g,
                                   (__attribute__((address_space(3))) void*)l, 16, 0, 0);
}

// ------- fused: GroupNorm partial sums (blocks 0..1023, no atomics/memset)
//         + f32->bf16 weight cast (blocks 1024..2047) -------
__global__ void gn_cast(const float* __restrict__ x, float* __restrict__ pstats,
                        const float* __restrict__ s0, const float* __restrict__ s1,
                        const float* __restrict__ s2, const float* __restrict__ s3,
                        unsigned short* __restrict__ dst) {
  int bid = blockIdx.x;
  int t = threadIdx.x;
  if (bid < 1024) {
    int bg = bid >> 4, row = bid & 15;
    int b = bg >> 5, g = bg & 31;
    const float* base = x + ((size_t)(b * C_ + g * 16 + row)) * HW_;
    float s = 0.f, s2 = 0.f;
    #pragma unroll
    for (int i = 0; i < 4; ++i) {
      float4 v = *reinterpret_cast<const float4*>(base + (size_t)(t + i * 256) * 4);
      s  += v.x + v.y + v.z + v.w;
      s2 += v.x * v.x + v.y * v.y + v.z * v.z + v.w * v.w;
    }
    for (int off = 32; off; off >>= 1) { s += __shfl_down(s, off); s2 += __shfl_down(s2, off); }
    __shared__ float rs[4], rs2[4];
    int w = t >> 6;
    if ((t & 63) == 0) { rs[w] = s; rs2[w] = s2; }
    __syncthreads();
    if (t == 0) {
      pstats[bid] = rs[0] + rs[1] + rs[2] + rs[3];
      pstats[1024 + bid] = rs2[0] + rs2[1] + rs2[2] + rs2[3];
    }
  } else {
    int cid = bid - 1024;
    int which = cid >> 8, bx = cid & 255;
    const float* src = which == 0 ? s0 : which == 1 ? s1 : which == 2 ? s2 : s3;
    int i = (bx * 256 + t) * 4;
    float4 v = *reinterpret_cast<const float4*>(src + i);
    ushort4 o; o.x = f2bf(v.x); o.y = f2bf(v.y); o.z = f2bf(v.z); o.w = f2bf(v.w);
    *reinterpret_cast<ushort4*>(dst + (size_t)which * 262144 + i) = o;
  }
}

// ------------- normalize + transpose: x(b,c,n) f32 -> t(b,n,c) bf16 -------------
__global__ void build_t(const float* __restrict__ x, const float* __restrict__ pstats,
                        const float* __restrict__ gamma, const float* __restrict__ beta,
                        unsigned short* __restrict__ tb) {
  __shared__ float lds[64 * 69];
  int n0 = blockIdx.x * 64, c0 = blockIdx.y * 64, b = blockIdx.z;
  int t = threadIdx.x;
  {
    int cl = t >> 2, ch = t & 3;
    int c = c0 + cl;
    int bg = b * 32 + (c >> 4);
    float s = 0.f, s2v = 0.f;
    #pragma unroll
    for (int r = 0; r < 16; ++r) {
      s   += pstats[bg * 16 + r];
      s2v += pstats[1024 + bg * 16 + r];
    }
    float mean = s * (1.f / 65536.f);
    float var = s2v * (1.f / 65536.f) - mean * mean;
    float rstd = rsqrtf(var + EPS_);
    float ga = gamma[c] * rstd;
    float be = beta[c] - mean * ga;
    const float* xr = x + ((size_t)(b * C_ + c)) * HW_ + n0 + ch * 16;
    #pragma unroll
    for (int i = 0; i < 4; ++i) {
      float4 v = *reinterpret_cast<const float4*>(xr + i * 4);
      int nl = ch * 16 + i * 4;
      lds[cl * 69 + nl + 0] = v.x * ga + be;
      lds[cl * 69 + nl + 1] = v.y * ga + be;
      lds[cl * 69 + nl + 2] = v.z * ga + be;
      lds[cl * 69 + nl + 3] = v.w * ga + be;
    }
  }
  __syncthreads();
  {
    int nl = t >> 2, cw = t & 3;
    unsigned short* orow = tb + ((size_t)(b * HW_ + n0 + nl)) * C_ + c0 + cw * 16;
    #pragma unroll
    for (int i = 0; i < 4; ++i) {
      ushort4 o4;
      o4.x = f2bf(lds[(cw * 16 + i * 4 + 0) * 69 + nl]);
      o4.y = f2bf(lds[(cw * 16 + i * 4 + 1) * 69 + nl]);
      o4.z = f2bf(lds[(cw * 16 + i * 4 + 2) * 69 + nl]);
      o4.w = f2bf(lds[(cw * 16 + i * 4 + 3) * 69 + nl]);
      *reinterpret_cast<ushort4*>(orow + i * 4) = o4;
    }
  }
}

// ---------------- fused Q/K/V^T projections, one launch (XCD-grouped) ----------------
__global__ __launch_bounds__(256, 2) void gemm_qkv(
    const unsigned short* __restrict__ tb, const unsigned short* __restrict__ wqkv,
    const float* __restrict__ bq, const float* __restrict__ bk, const float* __restrict__ bv,
    unsigned short* __restrict__ qb, unsigned short* __restrict__ kb,
    unsigned short* __restrict__ vTb) {
  __shared__ unsigned short Al[2][128 * 64];
  __shared__ unsigned short Bl[2][128 * 64];
  // bijective remap of 768 blocks: xcd = f&7 fixed; i>>2 selects (y,z) combo, i&3 the x
  int f = blockIdx.x + 4 * (blockIdx.y + 32 * blockIdx.z);
  int xcd = f & 7, i = f >> 3;
  int bx = i & 3;
  int g = xcd * 24 + (i >> 2);     // 0..191
  int bz = g >> 5, by = g & 31;
  int which = bz >> 1, b = bz & 1;
  const unsigned short* Ab = (which < 2) ? (tb + (size_t)b * HW_ * K_) : (wqkv + 2 * 262144);
  const unsigned short* Bb = (which < 2) ? (wqkv + which * 262144) : (tb + (size_t)b * HW_ * K_);
  int m0 = (which < 2) ? by * 128 : bx * 128;
  int n0 = (which < 2) ? bx * 128 : by * 128;
  int N = (which < 2) ? 512 : HW_;
  unsigned short* Cb = (which == 0) ? (qb + (size_t)b * HW_ * K_)
                     : (which == 1) ? (kb + (size_t)b * HW_ * K_)
                                    : (vTb + (size_t)b * C_ * HW_);
  const float* bias = (which == 0) ? bq : (which == 1) ? bk : bv;
  int t = threadIdx.x, lane = t & 63, w = t >> 6;
  int l15 = lane & 15, quad = lane >> 4;
  int mw = (w & 1) * 64, nw = (w >> 1) * 64;
  int sr8 = lane >> 3, sb = lane & 7;
  f32x4 acc[4][4] = {};

  #define G_STAGE(KC) do {                                                          \
    int pb = (KC) & 1;                                                              \
    _Pragma("unroll")                                                               \
    for (int q = 0; q < 4; ++q) {                                                   \
      int row = w * 32 + q * 8 + sr8;                                               \
      int gb = sb ^ (row & 7);                                                      \
      gld_lds16(Ab + (size_t)(m0 + row) * K_ + (KC) * 64 + gb * 8, &Al[pb][(w * 32 + q * 8) * 64]); \
      gld_lds16(Bb + (size_t)(n0 + row) * K_ + (KC) * 64 + gb * 8, &Bl[pb][(w * 32 + q * 8) * 64]); \
    }                                                                               \
  } while (0)

  G_STAGE(0);
  __syncthreads();
  for (int kc = 0; kc < 8; ++kc) {
    if (kc < 7) G_STAGE(kc + 1);
    const unsigned short* Ac = Al[kc & 1];
    const unsigned short* Bc = Bl[kc & 1];
    #pragma unroll
    for (int kk = 0; kk < 2; ++kk) {
      bf16x8 af[4];
      #pragma unroll
      for (int mt = 0; mt < 4; ++mt)
        af[mt] = *reinterpret_cast<const bf16x8*>(
            &Ac[(mw + mt * 16 + l15) * 64 + (((kk * 4 + quad) ^ (l15 & 7)) << 3)]);
      #pragma unroll
      for (int nt = 0; nt < 4; ++nt) {
        bf16x8 bfr = *reinterpret_cast<const bf16x8*>(
            &Bc[(nw + nt * 16 + l15) * 64 + (((kk * 4 + quad) ^ (l15 & 7)) << 3)]);
        #pragma unroll
        for (int mt = 0; mt < 4; ++mt)
          acc[mt][nt] = __builtin_amdgcn_mfma_f32_16x16x32_bf16(af[mt], bfr, acc[mt][nt], 0, 0, 0);
      }
    }
    __syncthreads();
  }
  #undef G_STAGE
  #pragma unroll
  for (int mt = 0; mt < 4; ++mt)
    #pragma unroll
    for (int nt = 0; nt < 4; ++nt)
      #pragma unroll
      for (int rr = 0; rr < 4; ++rr) {
        int row = m0 + mw + mt * 16 + quad * 4 + rr;
        int col = n0 + nw + nt * 16 + l15;
        float v = acc[mt][nt][rr] + ((which < 2) ? bias[col] : bias[row]);
        Cb[(size_t)row * N + col] = f2bf(v);
      }
}

// ---------------- final projection + residual, with fused opart merge ----------------
// 128x64 tiles -> 512 blocks -> 2 blocks/CU co-resident (r16-verified).
__global__ __launch_bounds__(256, 2) void gemm_fin(
    const unsigned short* __restrict__ A,            // wpb 512x512 bf16
    const unsigned short* __restrict__ opart,        // 4 parts (jh*2+z)
    const float* __restrict__ mpart, const float* __restrict__ lpart,
    const float* __restrict__ bias, const float* __restrict__ resid,
    float* __restrict__ out) {
  __shared__ unsigned short Al[2][128 * 64];
  __shared__ unsigned short Bl[2][64 * 68];    // padded: row stride 68 shorts
  int z = blockIdx.z;
  int n0 = blockIdx.x * 64, m0 = blockIdx.y * 128;
  int t = threadIdx.x, lane = t & 63, w = t >> 6;
  int l15 = lane & 15, quad = lane >> 4;
  int mw = (w & 1) * 64, nw = (w >> 1) * 32;   // 2 m-waves(64) x 2 n-waves(32)
  int sr8 = lane >> 3, sb = lane & 7;
  f32x4 acc[4][2] = {};

  float w0[2], w1[2];
  int nrow[2];
  #pragma unroll
  for (int q = 0; q < 2; ++q) {
    int n = n0 + w * 16 + q * 8 + sr8;
    nrow[q] = n;
    float ma = mpart[(size_t)z * HW_ + n], mb = mpart[(size_t)(2 + z) * HW_ + n];
    float la = lpart[(size_t)z * HW_ + n], lb = lpart[(size_t)(2 + z) * HW_ + n];
    float M = fmaxf(ma, mb);
    float ea = __expf(ma - M), eb = __expf(mb - M);
    float iv = 1.f / (la * ea + lb * eb);
    w0[q] = ea * iv; w1[q] = eb * iv;
  }
  const unsigned short* p0 = opart + (size_t)z * HW_ * 512;
  const unsigned short* p1 = opart + (size_t)(2 + z) * HW_ * 512;

  #define STAGE_A(KC) do {                                                          \
    int pb = (KC) & 1;                                                              \
    _Pragma("unroll")                                                               \
    for (int q = 0; q < 4; ++q) {                                                   \
      int row = w * 32 + q * 8 + sr8;                                               \
      int gb = sb ^ (row & 7);                                                      \
      gld_lds16(A + (size_t)(m0 + row) * K_ + (KC) * 64 + gb * 8, &Al[pb][(w * 32 + q * 8) * 64]); \
    }                                                                               \
  } while (0)

  #define STAGE_B(KC) do {                                                          \
    int pb = (KC) & 1;                                                              \
    _Pragma("unroll")                                                               \
    for (int q = 0; q < 2; ++q) {                                                   \
      int row = w * 16 + q * 8 + sr8;                                               \
      size_t goff = (size_t)nrow[q] * 512 + (KC) * 64 + sb * 8;                     \
      uint4 u0 = *reinterpret_cast<const uint4*>(p0 + goff);                        \
      uint4 u1 = *reinterpret_cast<const uint4*>(p1 + goff);                        \
      uint4 o4;                                                                     \
      unsigned* a0 = reinterpret_cast<unsigned*>(&u0);                              \
      unsigned* a1 = reinterpret_cast<unsigned*>(&u1);                              \
      unsigned* od = reinterpret_cast<unsigned*>(&o4);                              \
      _Pragma("unroll")                                                             \
      for (int j = 0; j < 4; ++j) {                                                 \
        float lo = bf2f((unsigned short)(a0[j] & 0xffffu)) * w0[q]                  \
                 + bf2f((unsigned short)(a1[j] & 0xffffu)) * w1[q];                 \
        float hi = bf2f((unsigned short)(a0[j] >> 16)) * w0[q]                      \
                 + bf2f((unsigned short)(a1[j] >> 16)) * w1[q];                     \
        od[j] = (unsigned)f2bf(lo) | ((unsigned)f2bf(hi) << 16);                    \
      }                                                                             \
      *reinterpret_cast<uint4*>(&Bl[pb][row * 68 + sb * 8]) = o4;                   \
    }                                                                               \
  } while (0)

  STAGE_A(0);
  STAGE_B(0);
  __syncthreads();
  for (int kc = 0; kc < 8; ++kc) {
    if (kc < 7) { STAGE_A(kc + 1); STAGE_B(kc + 1); }
    const unsigned short* Ac = Al[kc & 1];
    const unsigned short* Bc = Bl[kc & 1];
    #pragma unroll
    for (int kk = 0; kk < 2; ++kk) {
      bf16x8 af[4];
      #pragma unroll
      for (int mt = 0; mt < 4; ++mt)
        af[mt] = *reinterpret_cast<const bf16x8*>(
            &Ac[(mw + mt * 16 + l15) * 64 + (((kk * 4 + quad) ^ (l15 & 7)) << 3)]);
      #pragma unroll
      for (int nt = 0; nt < 2; ++nt) {
        bf16x8 bfr = *reinterpret_cast<const bf16x8*>(
            &Bc[(nw + nt * 16 + l15) * 68 + ((kk * 4 + quad) << 3)]);
        #pragma unroll
        for (int mt = 0; mt < 4; ++mt)
          acc[mt][nt] = __builtin_amdgcn_mfma_f32_16x16x32_bf16(af[mt], bfr, acc[mt][nt], 0, 0, 0);
      }
    }
    __syncthreads();
  }
  #undef STAGE_A
  #undef STAGE_B
  #pragma unroll
  for (int mt = 0; mt < 4; ++mt)
    #pragma unroll
    for (int nt = 0; nt < 2; ++nt)
      #pragma unroll
      for (int rr = 0; rr < 4; ++rr) {
        int row = m0 + mw + mt * 16 + quad * 4 + rr;
        int col = n0 + nw + nt * 16 + l15;
        size_t idx = (size_t)z * (C_ * HW_) + (size_t)row * HW_ + col;
        out[idx] = acc[mt][nt][rr] + bias[row] + resid[idx];
      }
}

// ------- flash attention r17: phase-PAIRED r10 form. 2 chunks per barrier phase,
// 4 rotating 32KB buffers (chunk g -> buf g%4; 16 chunks/it keeps rotation aligned).
// Barriers/it: 19 -> 11 (4 S + 4 PV + 3 softmax); prefetch slack doubles.
// Pl holds ONE 128-col jc-half (64x136, r12-verified trick); jc=1 half rewritten at
// PV chunk 2 from retained acc_s[4..7] (c=1 barrier makes write safe, c=3 barrier
// orders it before c=4's pa_r load). Math/layouts identical to verified r10.
__global__ __launch_bounds__(512, 2) void attn(
    const unsigned short* __restrict__ qg, const unsigned short* __restrict__ kg,
    const unsigned short* __restrict__ vg,  // vT: (b, c, n)
    unsigned short* __restrict__ opart, float* __restrict__ mpart, float* __restrict__ lpart) {
  __shared__ unsigned short KVb[4 * 16384];   // 4 x 32KB rotating chunk buffers
  __shared__ unsigned short Pl[64 * 136];     // one 128-j half + pad, 17408 B
  __shared__ float sm_m[64], sm_l[64], sm_alpha[64], sm_red[128];
  int qt = blockIdx.x, jh = blockIdx.y, b = blockIdx.z;
  int t = threadIdx.x, lane = t & 63, w = t >> 6;
  int l15 = lane & 15, quad = lane >> 4;
  int l31 = lane & 31, hl = lane >> 5;
  int rw = w & 3, cw = w >> 2;      // S phase: 4 row-groups(16) x 2 col-halves
  int rw2 = w & 1, dg = w >> 1;     // PV phase: 2 row-groups(32) x 4 d-slots
  int m0 = qt * 64;
  if (t < 64) { sm_m[t] = NEG_INF_; sm_l[t] = 0.f; }

  // staging geometry: thread stages 4 x 16B; wave w covers 1KB blocks w*4+q (4 rows each)
  int st_r[4], st_kb[4];
  #pragma unroll
  for (int q = 0; q < 4; ++q) {
    int blk = w * 4 + q;
    st_r[q] = blk * 4 + (lane >> 4);          // row 0..127 within chunk
    st_kb[q] = (lane & 15) ^ (st_r[q] & 7);   // logical 16B block (col/8)
  }

  #define STAGE_K(JC, KC, J0, BUF) do {                                             \
    const unsigned short* gb = kg + ((size_t)(b * HW_ + (J0) + (JC) * 128)) * K_ + (KC) * 128; \
    unsigned short* lb = KVb + ((BUF) << 14);                                       \
    _Pragma("unroll")                                                               \
    for (int q = 0; q < 4; ++q)                                                     \
      gld_lds16(gb + (size_t)st_r[q] * K_ + st_kb[q] * 8, lb + (w * 4 + q) * 512);  \
  } while (0)

  #define STAGE_V(DC, JC, J0, BUF) do {                                             \
    const unsigned short* gb = vg + ((size_t)(b * K_ + (DC) * 128)) * HW_ + (J0) + (JC) * 128; \
    unsigned short* lb = KVb + ((BUF) << 14);                                       \
    _Pragma("unroll")                                                               \
    for (int q = 0; q < 4; ++q)                                                     \
      gld_lds16(gb + (size_t)st_r[q] * HW_ + st_kb[q] * 8, lb + (w * 4 + q) * 512); \
  } while (0)

  bf16x8 qa[16];
  {
    const unsigned short* qrow = qg + ((size_t)(b * HW_ + m0 + rw * 16 + l15)) * K_ + quad * 8;
    #pragma unroll
    for (int kk = 0; kk < 16; ++kk)
      qa[kk] = *reinterpret_cast<const bf16x8*>(qrow + kk * 32);
  }
  f32x16 acc_o[4] = {};    // [dc]: d = dc*128 + dg*32 + l31

  int j0 = jh * 2048;
  STAGE_K(0, 0, j0, 0);    // S chunk 0 -> buf 0
  STAGE_K(0, 1, j0, 1);    // S chunk 1 -> buf 1
  __syncthreads();         // drains chunks 0,1; publishes sm init

  for (int it = 0; it < 8; ++it, j0 += 256) {
    f32x4 acc_s[8] = {};
    // ===== S: 8 chunks (jc=c>>2, kc=c&3), chunk c in buf c&3; barrier at odd c =====
    #pragma unroll
    for (int c = 0; c < 8; ++c) {
      if ((c & 1) == 0) {
        if (c < 6) {
          STAGE_K((c + 2) >> 2, (c + 2) & 3, j0, (c + 2) & 3);
          STAGE_K((c + 3) >> 2, (c + 3) & 3, j0, (c + 3) & 3);
        } else {           // c==6: stage PV chunks 0,1 (V dc=0,1 jc=0) -> bufs 0,1
          STAGE_V(0, 0, j0, 0);
          STAGE_V(1, 0, j0, 1);
        }
      }
      const unsigned short* bufc = KVb + ((c & 3) << 14);
      int jc = c >> 2, kc = c & 3;
      __builtin_amdgcn_s_setprio(1);
      #pragma unroll
      for (int kk = 0; kk < 4; ++kk)
        #pragma unroll
        for (int ct = 0; ct < 4; ++ct) {
          int jr = cw * 64 + ct * 16 + l15;
          bf16x8 bfr = *reinterpret_cast<const bf16x8*>(
              &bufc[jr * 128 + (((kk * 4 + quad) ^ (l15 & 7)) << 3)]);
          acc_s[jc * 4 + ct] = __builtin_amdgcn_mfma_f32_16x16x32_bf16(qa[kc * 4 + kk], bfr, acc_s[jc * 4 + ct], 0, 0, 0);
        }
      __builtin_amdgcn_s_setprio(0);
      if (c & 1) __syncthreads();
    }
    // ===== softmax =====
    float mx[4];
    #pragma unroll
    for (int rr = 0; rr < 4; ++rr) {
      float m = NEG_INF_;
      #pragma unroll
      for (int s = 0; s < 8; ++s) {
        acc_s[s][rr] *= SCALE_;
        m = fmaxf(m, acc_s[s][rr]);
      }
      mx[rr] = m;
    }
    #pragma unroll
    for (int off = 1; off < 16; off <<= 1)
      #pragma unroll
      for (int rr = 0; rr < 4; ++rr)
        mx[rr] = fmaxf(mx[rr], __shfl_xor(mx[rr], off));
    if (l15 == 0)
      #pragma unroll
      for (int rr = 0; rr < 4; ++rr)
        sm_red[cw * 64 + rw * 16 + quad * 4 + rr] = mx[rr];
    __syncthreads();
    if (t < 64) {
      float mnew = fmaxf(sm_m[t], fmaxf(sm_red[t], sm_red[64 + t]));
      sm_alpha[t] = __expf(sm_m[t] - mnew);
      sm_m[t] = mnew;
    }
    __syncthreads();
    float sum[4] = {0.f, 0.f, 0.f, 0.f};
    #pragma unroll
    for (int s = 0; s < 8; ++s)
      #pragma unroll
      for (int rr = 0; rr < 4; ++rr) {
        int rowl = rw * 16 + quad * 4 + rr;
        float p = __expf(acc_s[s][rr] - sm_m[rowl]);
        sum[rr] += p;
        if (s < 4)   // jc=0 half only; jc=1 rewritten mid-PV from acc_s[4..7]
          Pl[rowl * 136 + cw * 64 + (s & 3) * 16 + l15] = f2bf(p);
      }
    #pragma unroll
    for (int off = 1; off < 16; off <<= 1)
      #pragma unroll
      for (int rr = 0; rr < 4; ++rr)
        sum[rr] += __shfl_xor(sum[rr], off);
    if (l15 == 0)
      #pragma unroll
      for (int rr = 0; rr < 4; ++rr)
        sm_red[cw * 64 + rw * 16 + quad * 4 + rr] = sum[rr];
    __syncthreads();
    if (t < 64)
      sm_l[t] = sm_l[t] * sm_alpha[t] + sm_red[t] + sm_red[64 + t];
    // rescale O by alpha (32x32 C/D row mapping)
    #pragma unroll
    for (int r16 = 0; r16 < 16; ++r16) {
      int row = rw2 * 32 + (r16 & 3) + 8 * (r16 >> 2) + 4 * hl;
      float a = sm_alpha[row];
      #pragma unroll
      for (int dc = 0; dc < 4; ++dc)
        acc_o[dc][r16] *= a;
    }
    // ===== PV: 8 chunks (jc=c>>2, dc=c&3), global 8+c -> buf c&3; barrier at odd c =====
    bf16x8 pa_r[8];
    #pragma unroll
    for (int c = 0; c < 8; ++c) {
      if (c == 2) {
        // rewrite Pl with jc=1 half (jc0 reads done: pa_r loaded at c=0, barrier c=1;
        // reads of this data at c=4, after barrier c=3)
        #pragma unroll
        for (int s = 4; s < 8; ++s)
          #pragma unroll
          for (int rr = 0; rr < 4; ++rr) {
            int rowl = rw * 16 + quad * 4 + rr;
            Pl[rowl * 136 + cw * 64 + (s & 3) * 16 + l15] =
                f2bf(__expf(acc_s[s][rr] - sm_m[rowl]));
          }
      }
      if ((c & 3) == 0) {
        #pragma unroll
        for (int ksx = 0; ksx < 8; ++ksx)
          pa_r[ksx] = *reinterpret_cast<const bf16x8*>(
              &Pl[(rw2 * 32 + l31) * 136 + ksx * 16 + hl * 8]);
      }
      if ((c & 1) == 0) {
        if (c < 6) {
          STAGE_V((c + 2) & 3, (c + 2) >> 2, j0, (c + 2) & 3);
          STAGE_V((c + 3) & 3, (c + 3) >> 2, j0, (c + 3) & 3);
        } else if (it < 7) {   // c==6: stage next-it S chunks 0,1 -> bufs 0,1
          STAGE_K(0, 0, j0 + 256, 0);
          STAGE_K(0, 1, j0 + 256, 1);
        }
      }
      const unsigned short* bufc = KVb + ((c & 3) << 14);
      int dc = c & 3;
      __builtin_amdgcn_s_setprio(1);
      #pragma unroll
      for (int ksx = 0; ksx < 8; ++ksx) {
        bf16x8 vb = *reinterpret_cast<const bf16x8*>(
            &bufc[(dg * 32 + l31) * 128 + (((ksx * 2 + hl) ^ (l31 & 7)) << 3)]);
        acc_o[dc] = __builtin_amdgcn_mfma_f32_32x32x16_bf16(pa_r[ksx], vb, acc_o[dc], 0, 0, 0);
      }
      __builtin_amdgcn_s_setprio(0);
      if (c & 1) __syncthreads();
    }
  }
  #undef STAGE_K
  #undef STAGE_V
  // write partials (unnormalized O in bf16, running m and l)
  int part = jh * 2 + b;
  unsigned short* ob = opart + ((size_t)part * HW_ + m0) * 512;
  #pragma unroll
  for (int dc = 0; dc < 4; ++dc) {
    int d = dc * 128 + dg * 32 + l31;
    #pragma unroll
    for (int r16 = 0; r16 < 16; ++r16) {
      int row = rw2 * 32 + (r16 & 3) + 8 * (r16 >> 2) + 4 * hl;
      ob[(size_t)row * 512 + d] = f2bf(acc_o[dc][r16]);
    }
  }
  if (t < 64) {
    mpart[(size_t)part * HW_ + m0 + t] = sm_m[t];
    lpart[(size_t)part * HW_ + m0 + t] = sm_l[t];
  }
}

extern "C" void kernel_launch(void* const* d_in, const int* in_sizes, int n_in,
                              void* d_out, int out_size, void* d_ws, size_t ws_size,
                              hipStream_t stream) {
  const float* x     = (const float*)d_in[0];
  const float* gamma = (const float*)d_in[1];
  const float* beta  = (const float*)d_in[2];
  const float* wq    = (const float*)d_in[3];
  const float* bq    = (const float*)d_in[4];
  const float* wk    = (const float*)d_in[5];
  const float* bk    = (const float*)d_in[6];
  const float* wv    = (const float*)d_in[7];
  const float* bv    = (const float*)d_in[8];
  const float* wp    = (const float*)d_in[9];
  const float* bp    = (const float*)d_in[10];
  float* out = (float*)d_out;

  char* ws = (char*)d_ws;
  size_t o = 0;
  float* pstats         = (float*)(ws + o);          o += 8192;      // 2048 f32 partials
  unsigned short* tb    = (unsigned short*)(ws + o); o += 8388608;
  unsigned short* qb    = (unsigned short*)(ws + o); o += 8388608;
  unsigned short* kb    = (unsigned short*)(ws + o); o += 8388608;
  unsigned short* vTb   = (unsigned short*)(ws + o); o += 8388608;
  unsigned short* wqb   = (unsigned short*)(ws + o); o += 524288;
  unsigned short* wkb   = (unsigned short*)(ws + o); o += 524288;
  unsigned short* wvb   = (unsigned short*)(ws + o); o += 524288;
  unsigned short* wpb   = (unsigned short*)(ws + o); o += 524288;
  unsigned short* opart = (unsigned short*)(ws + o); o += 16777216;  // 4 parts bf16
  float* mpart          = (float*)(ws + o);          o += 65536;
  float* lpart          = (float*)(ws + o);          o += 65536;

  // fused groupnorm partial sums + weight cast (no memset, no atomics)
  gn_cast<<<2048, 256, 0, stream>>>(x, pstats, wq, wk, wv, wp, wqb);
  build_t<<<dim3(64, 8, 2), 256, 0, stream>>>(x, pstats, gamma, beta, tb);
  // fused q,k,vT projections (XCD-grouped)
  gemm_qkv<<<dim3(4, 32, 6), 256, 0, stream>>>(tb, wqb, bq, bk, bv, qb, kb, vTb);
  attn<<<dim3(64, 2, 2), 512, 0, stream>>>(qb, kb, vTb, opart, mpart, lpart);
  // final projection with fused partial-merge + residual (512 blocks -> 2/CU)
  gemm_fin<<<dim3(64, 4, 2), 256, 0, stream>>>(wpb, opart, mpart, lpart, bp, x, out);
}